// Round 3
// baseline (1635.418 us; speedup 1.0000x reference)
//
#include <hip/hip_runtime.h>
#include <hip/hip_bf16.h>
#include <math.h>

// BlockSparseAttention: x[1,4096,1024] fp32; w_qkv[3072,1024] fp32, b_qkv[3072] fp32,
// w_out[1024,1024] fp32, b_out[1024] fp32. out[4096,1024] fp32.
// blocks of 128; global blocks {0,24}; qb attends {0,qb,24} (or all if qb global).

#define SEQ 4096
#define DIM 1024
#define NHEADS 16
#define HDIM 64
#define BS 128
#define NBLK 32      // SEQ/BS
#define ROWS 32      // q rows per attention workgroup
#define KV_STRIDE 68 // 64 + 4 pad (float4-aligned, banks spread: 68%32=4)
#define S_STRIDE 132 // 128 + 4 pad

using short8 = __attribute__((ext_vector_type(8))) short;   // 8 x bf16 bits
using floatx4 = __attribute__((ext_vector_type(4))) float;

__device__ __forceinline__ float bf2f(short s) {
  unsigned u = ((unsigned)(unsigned short)s) << 16;
  return __uint_as_float(u);
}

// ---------------------------------------------------------------------------
// fp32 -> bf16 downcast (round-to-nearest-even via __float2bfloat16)
// ---------------------------------------------------------------------------
__global__ __launch_bounds__(256) void downcast(const float* __restrict__ src,
                                                __hip_bfloat16* __restrict__ dst,
                                                int n) {
  int i = (blockIdx.x * 256 + threadIdx.x) * 4;
  if (i >= n) return;
  float4 v = *(const float4*)(src + i);
  __hip_bfloat16 b0 = __float2bfloat16(v.x);
  __hip_bfloat16 b1 = __float2bfloat16(v.y);
  __hip_bfloat16 b2 = __float2bfloat16(v.z);
  __hip_bfloat16 b3 = __float2bfloat16(v.w);
  ushort4 packed = {*(unsigned short*)&b0, *(unsigned short*)&b1,
                    *(unsigned short*)&b2, *(unsigned short*)&b3};
  *(ushort4*)(((unsigned short*)dst) + i) = packed;
}

// ---------------------------------------------------------------------------
// GEMM: C[M,N] = A[M,K] @ W[N,K]^T + bias[N].  One wave per 16x16 C tile,
// mfma_f32_16x16x32_bf16, fragments loaded directly from global (bf16).
// A-frag: lane holds A[m = lane&15][k = (lane>>4)*8 + j], j=0..7 (16B load).
// B-frag: lane holds W[n = lane&15][k = (lane>>4)*8 + j]  (W is [N][K] = B^T).
// D: row = (lane>>4)*4 + i, col = lane&15   [guide §3, m89/m91 verified]
// ---------------------------------------------------------------------------
__global__ __launch_bounds__(256) void gemm_qkv(const __hip_bfloat16* __restrict__ X,
                                                const __hip_bfloat16* __restrict__ W,
                                                const float* __restrict__ B,
                                                __hip_bfloat16* __restrict__ qkv) {
  const int Kd = DIM;
  int lane = threadIdx.x & 63;
  int wv = threadIdx.x >> 6;
  int ntile = blockIdx.x * 4 + wv;     // 4 waves -> 64 cols per block
  int mtile = blockIdx.y;
  int fr = lane & 15;
  int quad = lane >> 4;
  const short8* ap = (const short8*)(X + (size_t)(mtile * 16 + fr) * Kd + quad * 8);
  const short8* bp = (const short8*)(W + (size_t)(ntile * 16 + fr) * Kd + quad * 8);
  floatx4 acc = {0.f, 0.f, 0.f, 0.f};
  for (int kk = 0; kk < Kd / 32; ++kk) {
    short8 a = ap[kk * 4];   // advance 32 bf16 = 4 short8 per k-step
    short8 b = bp[kk * 4];
    acc = __builtin_amdgcn_mfma_f32_16x16x32_bf16(a, b, acc, 0, 0, 0);
  }
  int ncol = ntile * 16 + fr;          // D col = lane&15
  float bv = B[ncol];
  int s = ncol >> 10;                  // 0=Q,1=K,2=V
  int c = ncol & 1023;                 // h*64 + d
  __hip_bfloat16* dst = qkv + (size_t)s * SEQ * DIM + c;
  int m0 = mtile * 16 + quad * 4;
#pragma unroll
  for (int i = 0; i < 4; ++i) {
    dst[(size_t)(m0 + i) * DIM] = __float2bfloat16(acc[i] + bv);
  }
}

__global__ __launch_bounds__(256) void gemm_out(const __hip_bfloat16* __restrict__ A,
                                                const __hip_bfloat16* __restrict__ W,
                                                const float* __restrict__ B,
                                                float* __restrict__ out) {
  const int Kd = DIM;
  int lane = threadIdx.x & 63;
  int wv = threadIdx.x >> 6;
  int ntile = blockIdx.x * 4 + wv;
  int mtile = blockIdx.y;
  int fr = lane & 15;
  int quad = lane >> 4;
  const short8* ap = (const short8*)(A + (size_t)(mtile * 16 + fr) * Kd + quad * 8);
  const short8* bp = (const short8*)(W + (size_t)(ntile * 16 + fr) * Kd + quad * 8);
  floatx4 acc = {0.f, 0.f, 0.f, 0.f};
  for (int kk = 0; kk < Kd / 32; ++kk) {
    short8 a = ap[kk * 4];
    short8 b = bp[kk * 4];
    acc = __builtin_amdgcn_mfma_f32_16x16x32_bf16(a, b, acc, 0, 0, 0);
  }
  int ncol = ntile * 16 + fr;
  float bv = B[ncol];
  int m0 = mtile * 16 + quad * 4;
#pragma unroll
  for (int i = 0; i < 4; ++i) {
    out[(size_t)(m0 + i) * DIM + ncol] = acc[i] + bv;   // fp32 output
  }
}

// ---------------------------------------------------------------------------
// Block-sparse flash attention. Grid: (SEQ/ROWS, NHEADS), 256 threads.
// Thread t -> q-row r = t>>3 (32 rows), group g = t&7.
//   Phase A: thread computes scores for keys {g + 8j, j=0..15} (fp32, Q in regs)
//   Phase B: 8-lane shfl_xor row reduce -> online softmax, p -> LDS
//   Phase C: thread accumulates dims d = g*8..g*8+7 over all 128 keys
// K then V staged (bf16 global -> fp32 LDS) through the same 34KB buffer.
// ---------------------------------------------------------------------------
__global__ __launch_bounds__(256) void attn(const __hip_bfloat16* __restrict__ qkv,
                                            __hip_bfloat16* __restrict__ aout) {
  __shared__ float kv_lds[BS * KV_STRIDE];   // 34816 B
  __shared__ float s_lds[ROWS * S_STRIDE];   // 16896 B
  const int h = blockIdx.y;
  const int chunk = blockIdx.x;
  const int q0 = chunk * ROWS;
  const int qb = q0 / BS;
  const int t = threadIdx.x;
  const int r = t >> 3;
  const int g = t & 7;

  // Q row (pre-scaled by 1/sqrt(64)) into registers
  const __hip_bfloat16* qrow = qkv + (size_t)(q0 + r) * DIM + h * HDIM;
  float qreg[HDIM];
#pragma unroll
  for (int d = 0; d < HDIM; d += 8) {
    short8 raw = *(const short8*)(qrow + d);
#pragma unroll
    for (int j = 0; j < 8; ++j) qreg[d + j] = bf2f(raw[j]) * 0.125f;
  }

  const bool qglobal = (qb == 0 || qb == 24);
  const int nkb = qglobal ? NBLK : 3;

  float mrow = -INFINITY, lsum = 0.f;
  float oacc[8] = {0.f, 0.f, 0.f, 0.f, 0.f, 0.f, 0.f, 0.f};

  for (int bi = 0; bi < nkb; ++bi) {
    int kb = qglobal ? bi : (bi == 0 ? 0 : (bi == 1 ? qb : 24));

    // ---- stage K block (bf16 -> fp32 LDS) ----
    const __hip_bfloat16* kbase =
        qkv + (size_t)SEQ * DIM + (size_t)(kb * BS) * DIM + h * HDIM;
    __syncthreads();  // prior phase C done with kv_lds / s_lds
    for (int i = t; i < BS * HDIM / 8; i += 256) {
      int rr = i >> 3;
      int c8 = (i & 7) * 8;
      short8 raw = *(const short8*)(kbase + (size_t)rr * DIM + c8);
      float* d = &kv_lds[rr * KV_STRIDE + c8];
#pragma unroll
      for (int j = 0; j < 8; ++j) d[j] = bf2f(raw[j]);
    }
    __syncthreads();

    // ---- phase A: scores ----
    float sc[16];
#pragma unroll
    for (int j = 0; j < 16; ++j) {
      int key = g + 8 * j;
      const float* krow = &kv_lds[key * KV_STRIDE];
      float s0 = 0.f, s1 = 0.f, s2 = 0.f, s3 = 0.f;
#pragma unroll
      for (int d = 0; d < HDIM; d += 4) {
        float4 k4 = *(const float4*)(krow + d);
        s0 += qreg[d] * k4.x;
        s1 += qreg[d + 1] * k4.y;
        s2 += qreg[d + 2] * k4.z;
        s3 += qreg[d + 3] * k4.w;
      }
      sc[j] = (s0 + s1) + (s2 + s3);
    }

    // ---- phase B: online softmax ----
    float rmax = sc[0];
#pragma unroll
    for (int j = 1; j < 16; ++j) rmax = fmaxf(rmax, sc[j]);
#pragma unroll
    for (int off = 1; off < 8; off <<= 1) rmax = fmaxf(rmax, __shfl_xor(rmax, off, 64));
    float newm = fmaxf(mrow, rmax);
    float alpha = __expf(mrow - newm);   // exp(-inf)=0 on first block
    float psum = 0.f;
#pragma unroll
    for (int j = 0; j < 16; ++j) {
      float p = __expf(sc[j] - newm);
      psum += p;
      s_lds[r * S_STRIDE + g + 8 * j] = p;
    }
#pragma unroll
    for (int off = 1; off < 8; off <<= 1) psum += __shfl_xor(psum, off, 64);
    lsum = lsum * alpha + psum;
    mrow = newm;
    __syncthreads();  // p visible; everyone done reading K

    // ---- stage V block (reuse kv_lds, bf16 -> fp32) ----
    const __hip_bfloat16* vbase =
        qkv + 2ull * SEQ * DIM + (size_t)(kb * BS) * DIM + h * HDIM;
    for (int i = t; i < BS * HDIM / 8; i += 256) {
      int rr = i >> 3;
      int c8 = (i & 7) * 8;
      short8 raw = *(const short8*)(vbase + (size_t)rr * DIM + c8);
      float* d = &kv_lds[rr * KV_STRIDE + c8];
#pragma unroll
      for (int j = 0; j < 8; ++j) d[j] = bf2f(raw[j]);
    }
    __syncthreads();

    // ---- phase C: PV accumulate ----
#pragma unroll
    for (int j = 0; j < 8; ++j) oacc[j] *= alpha;
    const float* srow = &s_lds[r * S_STRIDE];
    for (int k = 0; k < BS; ++k) {
      float p = srow[k];
      const float* vrow = &kv_lds[k * KV_STRIDE + g * 8];
      float4 va = *(const float4*)(vrow);
      float4 vb = *(const float4*)(vrow + 4);
      oacc[0] += p * va.x;
      oacc[1] += p * va.y;
      oacc[2] += p * va.z;
      oacc[3] += p * va.w;
      oacc[4] += p * vb.x;
      oacc[5] += p * vb.y;
      oacc[6] += p * vb.z;
      oacc[7] += p * vb.w;
    }
  }

  float inv = 1.f / lsum;
  __hip_bfloat16* orow = aout + (size_t)(q0 + r) * DIM + h * HDIM + g * 8;
#pragma unroll
  for (int j = 0; j < 8; ++j) orow[j] = __float2bfloat16(oacc[j] * inv);
}

// ---------------------------------------------------------------------------
extern "C" void kernel_launch(void* const* d_in, const int* in_sizes, int n_in,
                              void* d_out, int out_size, void* d_ws, size_t ws_size,
                              hipStream_t stream) {
  const float* x = (const float*)d_in[0];
  const float* w_qkv = (const float*)d_in[1];
  const float* b_qkv = (const float*)d_in[2];
  const float* w_out = (const float*)d_in[3];
  const float* b_out = (const float*)d_in[4];
  float* out = (float*)d_out;   // reference output dtype is float32

  // ws layout (bytes):
  //   [0,   24M) bf16 qkv        [3][SEQ][DIM]
  //   [24M, 32M) bf16 x          [SEQ][DIM]
  //   [32M, 38M) bf16 w_qkv      [3*DIM][DIM]
  //   [38M, 40M) bf16 w_out      [DIM][DIM]
  //   [40M, 48M) bf16 attn_out   [SEQ][DIM]
  char* wsb = (char*)d_ws;
  __hip_bfloat16* qkv_ws = (__hip_bfloat16*)(wsb);
  __hip_bfloat16* x_bf = (__hip_bfloat16*)(wsb + 24ull * 1024 * 1024);
  __hip_bfloat16* wqkv_bf = (__hip_bfloat16*)(wsb + 32ull * 1024 * 1024);
  __hip_bfloat16* wout_bf = (__hip_bfloat16*)(wsb + 38ull * 1024 * 1024);
  __hip_bfloat16* attn_ws = (__hip_bfloat16*)(wsb + 40ull * 1024 * 1024);

  dim3 blk(256);
  downcast<<<dim3(SEQ * DIM / 1024), blk, 0, stream>>>(x, x_bf, SEQ * DIM);
  downcast<<<dim3(3 * DIM * DIM / 1024), blk, 0, stream>>>(w_qkv, wqkv_bf, 3 * DIM * DIM);
  downcast<<<dim3(DIM * DIM / 1024), blk, 0, stream>>>(w_out, wout_bf, DIM * DIM);
  gemm_qkv<<<dim3(3 * DIM / 64, SEQ / 16), blk, 0, stream>>>(x_bf, wqkv_bf, b_qkv, qkv_ws);
  attn<<<dim3(SEQ / ROWS, NHEADS), blk, 0, stream>>>(qkv_ws, attn_ws);
  gemm_out<<<dim3(DIM / 64, SEQ / 16), blk, 0, stream>>>(attn_ws, wout_bf, b_out, out);
}

// Round 4
// 626.071 us; speedup vs baseline: 2.6122x; 2.6122x over previous
//
#include <hip/hip_runtime.h>
#include <hip/hip_bf16.h>
#include <math.h>

// BlockSparseAttention: x[1,4096,1024] fp32; w_qkv[3072,1024], b_qkv[3072],
// w_out[1024,1024], b_out[1024] fp32. out[4096,1024] fp32.
// blocks of 128; global blocks {0,24}; qb attends {0,qb,24} (or all if qb global).

#define SEQ 4096
#define DIM 1024
#define NHEADS 16
#define HDIM 64
#define BS 128
#define PSTRIDE 136   // 128 + 8 bf16 pad; 272B row stride keeps 16B align for b128

using short8 = __attribute__((ext_vector_type(8))) short;   // 8 x bf16 bits
using floatx4 = __attribute__((ext_vector_type(4))) float;

// ---------------------------------------------------------------------------
// fp32 -> bf16 downcast
// ---------------------------------------------------------------------------
__global__ __launch_bounds__(256) void downcast(const float* __restrict__ src,
                                                __hip_bfloat16* __restrict__ dst,
                                                int n) {
  int i = (blockIdx.x * 256 + threadIdx.x) * 4;
  if (i >= n) return;
  float4 v = *(const float4*)(src + i);
  __hip_bfloat16 b0 = __float2bfloat16(v.x);
  __hip_bfloat16 b1 = __float2bfloat16(v.y);
  __hip_bfloat16 b2 = __float2bfloat16(v.z);
  __hip_bfloat16 b3 = __float2bfloat16(v.w);
  ushort4 packed = {*(unsigned short*)&b0, *(unsigned short*)&b1,
                    *(unsigned short*)&b2, *(unsigned short*)&b3};
  *(ushort4*)(((unsigned short*)dst) + i) = packed;
}

// ---------------------------------------------------------------------------
// QKV GEMM: one wave per 16x16 C tile, mfma_f32_16x16x32_bf16.
// A-frag: A[m=lane&15][k=quad*8+j]; B-frag: W[n=lane&15][k=quad*8+j].
// D: row=quad*4+i, col=lane&15. Q,K written row-major; V written TRANSPOSED
// (Vt[dim][seq]) so the attention PV B-operand is a direct 16B load.
// ---------------------------------------------------------------------------
__global__ __launch_bounds__(256) void gemm_qkv(const __hip_bfloat16* __restrict__ X,
                                                const __hip_bfloat16* __restrict__ W,
                                                const float* __restrict__ B,
                                                __hip_bfloat16* __restrict__ qkv) {
  const int Kd = DIM;
  int lane = threadIdx.x & 63;
  int wv = threadIdx.x >> 6;
  int ntile = blockIdx.x * 4 + wv;
  int mtile = blockIdx.y;
  int fr = lane & 15;
  int quad = lane >> 4;
  const short8* ap = (const short8*)(X + (size_t)(mtile * 16 + fr) * Kd + quad * 8);
  const short8* bp = (const short8*)(W + (size_t)(ntile * 16 + fr) * Kd + quad * 8);
  floatx4 acc = {0.f, 0.f, 0.f, 0.f};
  for (int kk = 0; kk < Kd / 32; ++kk) {
    short8 a = ap[kk * 4];
    short8 b = bp[kk * 4];
    acc = __builtin_amdgcn_mfma_f32_16x16x32_bf16(a, b, acc, 0, 0, 0);
  }
  int ncol = ntile * 16 + fr;          // wave-uniform s (tile never crosses 1024)
  float bv = B[ncol];
  int s = ncol >> 10;                  // 0=Q,1=K,2=V
  int c = ncol & 1023;
  int m0 = mtile * 16 + quad * 4;
  if (s == 2) {
    // transposed: Vt[c][m0..m0+3], contiguous 4 bf16 -> one 8B store
    __hip_bfloat16* vt = qkv + 2ull * SEQ * DIM;
    ushort4 pk;
    unsigned short* pks = (unsigned short*)&pk;
#pragma unroll
    for (int i = 0; i < 4; ++i) {
      __hip_bfloat16 bb = __float2bfloat16(acc[i] + bv);
      pks[i] = *(unsigned short*)&bb;
    }
    *(ushort4*)(vt + (size_t)c * SEQ + m0) = pk;
  } else {
    __hip_bfloat16* dst = qkv + (size_t)s * SEQ * DIM + c;
#pragma unroll
    for (int i = 0; i < 4; ++i) {
      dst[(size_t)(m0 + i) * DIM] = __float2bfloat16(acc[i] + bv);
    }
  }
}

__global__ __launch_bounds__(256) void gemm_out(const __hip_bfloat16* __restrict__ A,
                                                const __hip_bfloat16* __restrict__ W,
                                                const float* __restrict__ B,
                                                float* __restrict__ out) {
  const int Kd = DIM;
  int lane = threadIdx.x & 63;
  int wv = threadIdx.x >> 6;
  int ntile = blockIdx.x * 4 + wv;
  int mtile = blockIdx.y;
  int fr = lane & 15;
  int quad = lane >> 4;
  const short8* ap = (const short8*)(A + (size_t)(mtile * 16 + fr) * Kd + quad * 8);
  const short8* bp = (const short8*)(W + (size_t)(ntile * 16 + fr) * Kd + quad * 8);
  floatx4 acc = {0.f, 0.f, 0.f, 0.f};
  for (int kk = 0; kk < Kd / 32; ++kk) {
    short8 a = ap[kk * 4];
    short8 b = bp[kk * 4];
    acc = __builtin_amdgcn_mfma_f32_16x16x32_bf16(a, b, acc, 0, 0, 0);
  }
  int ncol = ntile * 16 + fr;
  float bv = B[ncol];
  int m0 = mtile * 16 + quad * 4;
#pragma unroll
  for (int i = 0; i < 4; ++i) {
    out[(size_t)(m0 + i) * DIM + ncol] = acc[i] + bv;
  }
}

// ---------------------------------------------------------------------------
// MFMA flash attention with KV-split.
// Grid: (92, 16heads) x 256 thr. Wave wv owns rows [q0+wv*16, +16) end-to-end.
//   wgid <  60 : non-global qb (30 qb x 2 halves), KV list {0, qb, 24}, writes
//                normalized bf16 directly to aout.
//   wgid >= 60 : global qb 0/24 (2 qb x 2 halves x 8 slices of 4 KV blocks),
//                writes partial (o fp32 unnormalized, m, l) for combine.
// Per KV block (wave-local): S=Q K^T via 16 MFMA (8 ntiles x 2 ksteps);
// in-wave online softmax (shfl over 16-lane groups); P -> LDS (bf16) ->
// A-frags; O += P V via 16 MFMA with B-frags straight from global Vt.
// No __syncthreads anywhere.
// ---------------------------------------------------------------------------
__global__ __launch_bounds__(256) void attn_mfma(
    const __hip_bfloat16* __restrict__ qkv,
    __hip_bfloat16* __restrict__ aout,
    float* __restrict__ po, float* __restrict__ pm, float* __restrict__ pl) {
  __shared__ __hip_bfloat16 p_lds[4 * 16 * PSTRIDE];  // 17408 B
  const int h = blockIdx.y;
  const int wgid = blockIdx.x;
  const int t = threadIdx.x;
  const int wv = t >> 6;
  const int lane = t & 63;
  const int fr = lane & 15;
  const int quad = lane >> 4;

  int qb, q0, niter, slice = 0, pid = 0;
  bool direct;
  if (wgid < 60) {
    int nb = wgid >> 1;                 // 0..29
    qb = (nb < 23) ? nb + 1 : nb + 2;   // 1..23, 25..31
    q0 = qb * BS + (wgid & 1) * 64;
    niter = 3;
    direct = true;
  } else {
    int gi = wgid - 60;                 // 0..31
    slice = gi & 7;
    int chunk = gi >> 3;                // 0..3
    qb = (chunk >> 1) * 24;             // 0 or 24
    q0 = qb * BS + (chunk & 1) * 64;
    niter = 4;
    direct = false;
    pid = (h * 4 + chunk) * 8 + slice;
  }

  const __hip_bfloat16* Q = qkv;
  const __hip_bfloat16* K = qkv + (size_t)SEQ * DIM;
  const __hip_bfloat16* Vt = qkv + 2ull * SEQ * DIM;  // [DIM][SEQ]

  // Q A-frags, 2 k-steps (dims 0-31, 32-63)
  short8 qa0, qa1;
  {
    const __hip_bfloat16* qp =
        Q + (size_t)(q0 + wv * 16 + fr) * DIM + h * HDIM + quad * 8;
    qa0 = *(const short8*)(qp);
    qa1 = *(const short8*)(qp + 32);
  }

  float mrow[4] = {-INFINITY, -INFINITY, -INFINITY, -INFINITY};
  float lsum[4] = {0.f, 0.f, 0.f, 0.f};
  floatx4 o[4];
#pragma unroll
  for (int i = 0; i < 4; ++i) o[i] = (floatx4){0.f, 0.f, 0.f, 0.f};

  __hip_bfloat16* pbase = &p_lds[wv * 16 * PSTRIDE];

  for (int bi = 0; bi < niter; ++bi) {
    int kb = direct ? (bi == 0 ? 0 : (bi == 1 ? qb : 24)) : slice * 4 + bi;

    // ---- QK^T ----
    floatx4 s[8];
    const __hip_bfloat16* kp = K + (size_t)(kb * BS + fr) * DIM + h * HDIM + quad * 8;
#pragma unroll
    for (int nt = 0; nt < 8; ++nt) {
      const __hip_bfloat16* kr = kp + (size_t)nt * 16 * DIM;
      short8 kf0 = *(const short8*)(kr);
      short8 kf1 = *(const short8*)(kr + 32);
      floatx4 acc = {0.f, 0.f, 0.f, 0.f};
      acc = __builtin_amdgcn_mfma_f32_16x16x32_bf16(qa0, kf0, acc, 0, 0, 0);
      acc = __builtin_amdgcn_mfma_f32_16x16x32_bf16(qa1, kf1, acc, 0, 0, 0);
      s[nt] = acc;
    }
    // scale 1/sqrt(64)
#pragma unroll
    for (int nt = 0; nt < 8; ++nt)
#pragma unroll
      for (int i = 0; i < 4; ++i) s[nt][i] *= 0.125f;

    // ---- in-wave online softmax (rows quad*4+i; reduce across fr lanes) ----
    float rmax[4];
#pragma unroll
    for (int i = 0; i < 4; ++i) {
      float m = s[0][i];
#pragma unroll
      for (int nt = 1; nt < 8; ++nt) m = fmaxf(m, s[nt][i]);
      rmax[i] = m;
    }
#pragma unroll
    for (int off = 1; off < 16; off <<= 1)
#pragma unroll
      for (int i = 0; i < 4; ++i)
        rmax[i] = fmaxf(rmax[i], __shfl_xor(rmax[i], off, 64));

    float newm[4], alpha[4], psum[4];
#pragma unroll
    for (int i = 0; i < 4; ++i) {
      newm[i] = fmaxf(mrow[i], rmax[i]);
      alpha[i] = __expf(mrow[i] - newm[i]);   // first iter: exp(-inf)=0
      psum[i] = 0.f;
    }
#pragma unroll
    for (int nt = 0; nt < 8; ++nt)
#pragma unroll
      for (int i = 0; i < 4; ++i) {
        float p = __expf(s[nt][i] - newm[i]);
        psum[i] += p;
        __hip_bfloat16 pb = __float2bfloat16(p);
        pbase[(quad * 4 + i) * PSTRIDE + nt * 16 + fr] = pb;
      }
#pragma unroll
    for (int off = 1; off < 16; off <<= 1)
#pragma unroll
      for (int i = 0; i < 4; ++i) psum[i] += __shfl_xor(psum[i], off, 64);
#pragma unroll
    for (int i = 0; i < 4; ++i) {
      lsum[i] = lsum[i] * alpha[i] + psum[i];
      mrow[i] = newm[i];
    }
    // rescale O
#pragma unroll
    for (int nt2 = 0; nt2 < 4; ++nt2)
#pragma unroll
      for (int i = 0; i < 4; ++i) o[nt2][i] *= alpha[i];

    // ---- P A-frags from LDS (same-wave RAW; compiler inserts lgkmcnt) ----
    short8 ap[4];
#pragma unroll
    for (int ks2 = 0; ks2 < 4; ++ks2)
      ap[ks2] = *(const short8*)&pbase[fr * PSTRIDE + ks2 * 32 + quad * 8];

    // ---- PV: B-frags straight from global Vt ----
    const __hip_bfloat16* vp =
        Vt + (size_t)(h * HDIM + fr) * SEQ + kb * BS + quad * 8;
#pragma unroll
    for (int nt2 = 0; nt2 < 4; ++nt2) {
      const __hip_bfloat16* vr = vp + (size_t)nt2 * 16 * SEQ;
#pragma unroll
      for (int ks2 = 0; ks2 < 4; ++ks2) {
        short8 vb = *(const short8*)(vr + ks2 * 32);
        o[nt2] = __builtin_amdgcn_mfma_f32_16x16x32_bf16(ap[ks2], vb, o[nt2], 0, 0, 0);
      }
    }
  }

  if (direct) {
    float inv[4];
#pragma unroll
    for (int i = 0; i < 4; ++i) inv[i] = 1.f / lsum[i];
#pragma unroll
    for (int nt2 = 0; nt2 < 4; ++nt2)
#pragma unroll
      for (int i = 0; i < 4; ++i)
        aout[(size_t)(q0 + wv * 16 + quad * 4 + i) * DIM + h * HDIM + nt2 * 16 + fr] =
            __float2bfloat16(o[nt2][i] * inv[i]);
  } else {
    float* pob = po + (size_t)pid * 4096 + (wv * 16 + quad * 4) * 64 + fr;
#pragma unroll
    for (int nt2 = 0; nt2 < 4; ++nt2)
#pragma unroll
      for (int i = 0; i < 4; ++i) pob[i * 64 + nt2 * 16] = o[nt2][i];
    if (fr == 0) {
#pragma unroll
      for (int i = 0; i < 4; ++i) {
        pm[pid * 64 + wv * 16 + quad * 4 + i] = mrow[i];
        pl[pid * 64 + wv * 16 + quad * 4 + i] = lsum[i];
      }
    }
  }
}

// ---------------------------------------------------------------------------
// Combine 8 KV-slice partials for the global q-blocks.
// Grid: 64 blocks (h*4+chunk) x 256 thr; thread: row=t>>2 (0..63), 16 dims.
// ---------------------------------------------------------------------------
__global__ __launch_bounds__(256) void combine(const float* __restrict__ po,
                                               const float* __restrict__ pm,
                                               const float* __restrict__ pl,
                                               __hip_bfloat16* __restrict__ aout) {
  int b = blockIdx.x;  // h*4 + chunk
  int h = b >> 2, chunk = b & 3;
  int t = threadIdx.x;
  int row = t >> 2;
  int d0 = (t & 3) * 16;

  float m8[8];
  float newm = -INFINITY;
#pragma unroll
  for (int s = 0; s < 8; ++s) {
    m8[s] = pm[(b * 8 + s) * 64 + row];
    newm = fmaxf(newm, m8[s]);
  }
  float wgt[8], lsum = 0.f;
#pragma unroll
  for (int s = 0; s < 8; ++s) {
    wgt[s] = __expf(m8[s] - newm);
    lsum += pl[(b * 8 + s) * 64 + row] * wgt[s];
  }
  float acc[16];
#pragma unroll
  for (int j = 0; j < 16; ++j) acc[j] = 0.f;
#pragma unroll
  for (int s = 0; s < 8; ++s) {
    const float* src = po + ((size_t)(b * 8 + s) * 4096) + row * 64 + d0;
#pragma unroll
    for (int j4 = 0; j4 < 4; ++j4) {
      float4 v = *(const float4*)(src + j4 * 4);
      acc[j4 * 4 + 0] += wgt[s] * v.x;
      acc[j4 * 4 + 1] += wgt[s] * v.y;
      acc[j4 * 4 + 2] += wgt[s] * v.z;
      acc[j4 * 4 + 3] += wgt[s] * v.w;
    }
  }
  float inv = 1.f / lsum;
  int qrow = (chunk >> 1) * 3072 + (chunk & 1) * 64 + row;
#pragma unroll
  for (int j = 0; j < 16; ++j)
    aout[(size_t)qrow * DIM + h * HDIM + d0 + j] = __float2bfloat16(acc[j] * inv);
}

// ---------------------------------------------------------------------------
extern "C" void kernel_launch(void* const* d_in, const int* in_sizes, int n_in,
                              void* d_out, int out_size, void* d_ws, size_t ws_size,
                              hipStream_t stream) {
  const float* x = (const float*)d_in[0];
  const float* w_qkv = (const float*)d_in[1];
  const float* b_qkv = (const float*)d_in[2];
  const float* w_out = (const float*)d_in[3];
  const float* b_out = (const float*)d_in[4];
  float* out = (float*)d_out;

  // ws layout (bytes):
  //   [0,   24M) bf16 qkv: Q[SEQ][DIM], K[SEQ][DIM], Vt[DIM][SEQ]
  //   [24M, 32M) bf16 x_bf        -- dead after gemm_qkv; reused as po (8MB fp32)
  //   [32M, 38M) bf16 wqkv_bf     -- dead after gemm_qkv; first 256KB reused as pm/pl
  //   [38M, 40M) bf16 wout_bf
  //   [40M, 48M) bf16 attn_ws     [SEQ][DIM]
  char* wsb = (char*)d_ws;
  __hip_bfloat16* qkv_ws = (__hip_bfloat16*)(wsb);
  __hip_bfloat16* x_bf = (__hip_bfloat16*)(wsb + 24ull * 1024 * 1024);
  __hip_bfloat16* wqkv_bf = (__hip_bfloat16*)(wsb + 32ull * 1024 * 1024);
  __hip_bfloat16* wout_bf = (__hip_bfloat16*)(wsb + 38ull * 1024 * 1024);
  __hip_bfloat16* attn_ws = (__hip_bfloat16*)(wsb + 40ull * 1024 * 1024);
  float* po = (float*)(wsb + 24ull * 1024 * 1024);           // 512*64*64*4 = 8MB
  float* pm = (float*)(wsb + 32ull * 1024 * 1024);           // 128KB
  float* pl = (float*)(wsb + 32ull * 1024 * 1024 + 131072);  // 128KB

  dim3 blk(256);
  downcast<<<dim3(SEQ * DIM / 1024), blk, 0, stream>>>(x, x_bf, SEQ * DIM);
  downcast<<<dim3(3 * DIM * DIM / 1024), blk, 0, stream>>>(w_qkv, wqkv_bf, 3 * DIM * DIM);
  downcast<<<dim3(DIM * DIM / 1024), blk, 0, stream>>>(w_out, wout_bf, DIM * DIM);
  gemm_qkv<<<dim3(3 * DIM / 64, SEQ / 16), blk, 0, stream>>>(x_bf, wqkv_bf, b_qkv, qkv_ws);
  attn_mfma<<<dim3(92, NHEADS), blk, 0, stream>>>(qkv_ws, attn_ws, po, pm, pl);
  combine<<<dim3(64), blk, 0, stream>>>(po, pm, pl, attn_ws);
  gemm_out<<<dim3(DIM / 64, SEQ / 16), blk, 0, stream>>>(attn_ws, wout_bf, b_out, out);
}

// Round 5
// 235.315 us; speedup vs baseline: 6.9499x; 2.6606x over previous
//
#include <hip/hip_runtime.h>
#include <hip/hip_bf16.h>
#include <math.h>

// BlockSparseAttention: x[1,4096,1024] fp32; w_qkv[3072,1024], b_qkv[3072],
// w_out[1024,1024], b_out[1024] fp32. out[4096,1024] fp32.
// blocks of 128; global blocks {0,24}; qb attends {0,qb,24} (or all if qb global).

#define SEQ 4096
#define DIM 1024
#define NHEADS 16
#define HDIM 64
#define BS 128
#define PSTRIDE 136   // 128 + 8 bf16 pad for attention P round-trip

using short8 = __attribute__((ext_vector_type(8))) short;   // 8 x bf16 bits
using floatx4 = __attribute__((ext_vector_type(4))) float;

__device__ __forceinline__ void gld_lds16(const __hip_bfloat16* g, __hip_bfloat16* l) {
  // 16B per lane, dest = wave-uniform base + lane*16 [guide §5, m97/m104]
  __builtin_amdgcn_global_load_lds(
      (const __attribute__((address_space(1))) unsigned int*)g,
      (__attribute__((address_space(3))) unsigned int*)l, 16, 0, 0);
}

// ---------------------------------------------------------------------------
// fp32 -> bf16 downcast
// ---------------------------------------------------------------------------
__global__ __launch_bounds__(256) void downcast(const float* __restrict__ src,
                                                __hip_bfloat16* __restrict__ dst,
                                                int n) {
  int i = (blockIdx.x * 256 + threadIdx.x) * 4;
  if (i >= n) return;
  float4 v = *(const float4*)(src + i);
  __hip_bfloat16 b0 = __float2bfloat16(v.x);
  __hip_bfloat16 b1 = __float2bfloat16(v.y);
  __hip_bfloat16 b2 = __float2bfloat16(v.z);
  __hip_bfloat16 b3 = __float2bfloat16(v.w);
  ushort4 packed = {*(unsigned short*)&b0, *(unsigned short*)&b1,
                    *(unsigned short*)&b2, *(unsigned short*)&b3};
  *(ushort4*)(((unsigned short*)dst) + i) = packed;
}

// ---------------------------------------------------------------------------
// m97-style 128x128 tiled GEMM: C[M,N] = A[M,K] @ W[N,K]^T + bias.
// 256 thr = 4 waves in 2x2; each wave owns a 64x64 quadrant = 4x4 MFMA tiles.
// BK=32: LDS 128x32 bf16 per operand (8KB each), staged via global_load_lds
// width=16, fully contiguous chunk layout (chunk c -> row c>>2, colchunk c&3).
// Per K-iter per wave: 8 ds_read_b128 + 16 MFMA  [m97 structure, 874 TF@4096^3]
// ---------------------------------------------------------------------------
#define GEMM_MAIN_LOOP(Kd)                                                     \
  __shared__ __align__(16) __hip_bfloat16 Asmem[128 * 32];                     \
  __shared__ __align__(16) __hip_bfloat16 Bsmem[128 * 32];                     \
  const int t = threadIdx.x;                                                   \
  const int w = t >> 6;                                                        \
  const int lane = t & 63;                                                     \
  const int fr = lane & 15;                                                    \
  const int quad = lane >> 4;                                                  \
  const int wm = w >> 1, wn = w & 1;                                           \
  const int m0 = blockIdx.y * 128;                                             \
  const int n0 = blockIdx.x * 128;                                             \
  const __hip_bfloat16* Ablk = Amat + (size_t)m0 * Kd;                         \
  const __hip_bfloat16* Bblk = Wmat + (size_t)n0 * Kd;                         \
  floatx4 acc[4][4];                                                           \
  _Pragma("unroll") for (int i = 0; i < 4; ++i)                                \
      _Pragma("unroll") for (int j = 0; j < 4; ++j)                            \
          acc[i][j] = (floatx4){0.f, 0.f, 0.f, 0.f};                           \
  for (int kk = 0; kk < Kd / 32; ++kk) {                                       \
    _Pragma("unroll") for (int j = 0; j < 2; ++j) {                            \
      int c = j * 256 + t;                                                     \
      int ldso = (j * 256 + w * 64) * 8;                                       \
      gld_lds16(Ablk + (size_t)(c >> 2) * Kd + kk * 32 + (c & 3) * 8,          \
                &Asmem[ldso]);                                                 \
      gld_lds16(Bblk + (size_t)(c >> 2) * Kd + kk * 32 + (c & 3) * 8,          \
                &Bsmem[ldso]);                                                 \
    }                                                                          \
    __syncthreads();                                                           \
    short8 af[4], bf_[4];                                                      \
    _Pragma("unroll") for (int mt = 0; mt < 4; ++mt)                           \
        af[mt] = *(const short8*)&Asmem[(wm * 64 + mt * 16 + fr) * 32 + quad * 8]; \
    _Pragma("unroll") for (int nt = 0; nt < 4; ++nt)                           \
        bf_[nt] = *(const short8*)&Bsmem[(wn * 64 + nt * 16 + fr) * 32 + quad * 8]; \
    _Pragma("unroll") for (int mt = 0; mt < 4; ++mt)                           \
        _Pragma("unroll") for (int nt = 0; nt < 4; ++nt)                       \
            acc[mt][nt] = __builtin_amdgcn_mfma_f32_16x16x32_bf16(             \
                af[mt], bf_[nt], acc[mt][nt], 0, 0, 0);                        \
    __syncthreads();                                                           \
  }

// QKV: writes Q,K row-major bf16; V transposed (Vt[dim][seq]).
__global__ __launch_bounds__(256) void gemm_qkv(const __hip_bfloat16* __restrict__ Amat,
                                                const __hip_bfloat16* __restrict__ Wmat,
                                                const float* __restrict__ Bias,
                                                __hip_bfloat16* __restrict__ qkv) {
  GEMM_MAIN_LOOP(DIM)
  __hip_bfloat16* vt = qkv + 2ull * SEQ * DIM;
#pragma unroll
  for (int nt = 0; nt < 4; ++nt) {
    int n = n0 + wn * 64 + nt * 16 + fr;
    float bv = Bias[n];
    int s = n >> 10;          // uniform within a 16-col tile (never crosses 1024)
    int cc = n & 1023;
#pragma unroll
    for (int mt = 0; mt < 4; ++mt) {
      int m = m0 + wm * 64 + mt * 16 + quad * 4;
      if (s == 2) {
        ushort4 pk;
        unsigned short* pks = (unsigned short*)&pk;
#pragma unroll
        for (int i = 0; i < 4; ++i) {
          __hip_bfloat16 bb = __float2bfloat16(acc[mt][nt][i] + bv);
          pks[i] = *(unsigned short*)&bb;
        }
        *(ushort4*)(vt + (size_t)cc * SEQ + m) = pk;
      } else {
        __hip_bfloat16* dst = qkv + (size_t)s * SEQ * DIM + cc;
#pragma unroll
        for (int i = 0; i < 4; ++i)
          dst[(size_t)(m + i) * DIM] = __float2bfloat16(acc[mt][nt][i] + bv);
      }
    }
  }
}

__global__ __launch_bounds__(256) void gemm_out(const __hip_bfloat16* __restrict__ Amat,
                                                const __hip_bfloat16* __restrict__ Wmat,
                                                const float* __restrict__ Bias,
                                                float* __restrict__ out) {
  GEMM_MAIN_LOOP(DIM)
#pragma unroll
  for (int nt = 0; nt < 4; ++nt) {
    int n = n0 + wn * 64 + nt * 16 + fr;
    float bv = Bias[n];
#pragma unroll
    for (int mt = 0; mt < 4; ++mt) {
      int m = m0 + wm * 64 + mt * 16 + quad * 4;
#pragma unroll
      for (int i = 0; i < 4; ++i)
        out[(size_t)(m + i) * DIM + n] = acc[mt][nt][i] + bv;
    }
  }
}

// ---------------------------------------------------------------------------
// MFMA flash attention with KV-split (unchanged from round 4).
// ---------------------------------------------------------------------------
__global__ __launch_bounds__(256) void attn_mfma(
    const __hip_bfloat16* __restrict__ qkv,
    __hip_bfloat16* __restrict__ aout,
    float* __restrict__ po, float* __restrict__ pm, float* __restrict__ pl) {
  __shared__ __hip_bfloat16 p_lds[4 * 16 * PSTRIDE];  // 17408 B
  const int h = blockIdx.y;
  const int wgid = blockIdx.x;
  const int t = threadIdx.x;
  const int wv = t >> 6;
  const int lane = t & 63;
  const int fr = lane & 15;
  const int quad = lane >> 4;

  int qb, q0, niter, slice = 0, pid = 0;
  bool direct;
  if (wgid < 60) {
    int nb = wgid >> 1;                 // 0..29
    qb = (nb < 23) ? nb + 1 : nb + 2;   // 1..23, 25..31
    q0 = qb * BS + (wgid & 1) * 64;
    niter = 3;
    direct = true;
  } else {
    int gi = wgid - 60;                 // 0..31
    slice = gi & 7;
    int chunk = gi >> 3;                // 0..3
    qb = (chunk >> 1) * 24;             // 0 or 24
    q0 = qb * BS + (chunk & 1) * 64;
    niter = 4;
    direct = false;
    pid = (h * 4 + chunk) * 8 + slice;
  }

  const __hip_bfloat16* Q = qkv;
  const __hip_bfloat16* K = qkv + (size_t)SEQ * DIM;
  const __hip_bfloat16* Vt = qkv + 2ull * SEQ * DIM;  // [DIM][SEQ]

  short8 qa0, qa1;
  {
    const __hip_bfloat16* qp =
        Q + (size_t)(q0 + wv * 16 + fr) * DIM + h * HDIM + quad * 8;
    qa0 = *(const short8*)(qp);
    qa1 = *(const short8*)(qp + 32);
  }

  float mrow[4] = {-INFINITY, -INFINITY, -INFINITY, -INFINITY};
  float lsum[4] = {0.f, 0.f, 0.f, 0.f};
  floatx4 o[4];
#pragma unroll
  for (int i = 0; i < 4; ++i) o[i] = (floatx4){0.f, 0.f, 0.f, 0.f};

  __hip_bfloat16* pbase = &p_lds[wv * 16 * PSTRIDE];

  for (int bi = 0; bi < niter; ++bi) {
    int kb = direct ? (bi == 0 ? 0 : (bi == 1 ? qb : 24)) : slice * 4 + bi;

    floatx4 s[8];
    const __hip_bfloat16* kp = K + (size_t)(kb * BS + fr) * DIM + h * HDIM + quad * 8;
#pragma unroll
    for (int nt = 0; nt < 8; ++nt) {
      const __hip_bfloat16* kr = kp + (size_t)nt * 16 * DIM;
      short8 kf0 = *(const short8*)(kr);
      short8 kf1 = *(const short8*)(kr + 32);
      floatx4 acc = {0.f, 0.f, 0.f, 0.f};
      acc = __builtin_amdgcn_mfma_f32_16x16x32_bf16(qa0, kf0, acc, 0, 0, 0);
      acc = __builtin_amdgcn_mfma_f32_16x16x32_bf16(qa1, kf1, acc, 0, 0, 0);
      s[nt] = acc;
    }
#pragma unroll
    for (int nt = 0; nt < 8; ++nt)
#pragma unroll
      for (int i = 0; i < 4; ++i) s[nt][i] *= 0.125f;

    float rmax[4];
#pragma unroll
    for (int i = 0; i < 4; ++i) {
      float m = s[0][i];
#pragma unroll
      for (int nt = 1; nt < 8; ++nt) m = fmaxf(m, s[nt][i]);
      rmax[i] = m;
    }
#pragma unroll
    for (int off = 1; off < 16; off <<= 1)
#pragma unroll
      for (int i = 0; i < 4; ++i)
        rmax[i] = fmaxf(rmax[i], __shfl_xor(rmax[i], off, 64));

    float newm[4], alpha[4], psum[4];
#pragma unroll
    for (int i = 0; i < 4; ++i) {
      newm[i] = fmaxf(mrow[i], rmax[i]);
      alpha[i] = __expf(mrow[i] - newm[i]);
      psum[i] = 0.f;
    }
#pragma unroll
    for (int nt = 0; nt < 8; ++nt)
#pragma unroll
      for (int i = 0; i < 4; ++i) {
        float p = __expf(s[nt][i] - newm[i]);
        psum[i] += p;
        __hip_bfloat16 pb = __float2bfloat16(p);
        pbase[(quad * 4 + i) * PSTRIDE + nt * 16 + fr] = pb;
      }
#pragma unroll
    for (int off = 1; off < 16; off <<= 1)
#pragma unroll
      for (int i = 0; i < 4; ++i) psum[i] += __shfl_xor(psum[i], off, 64);
#pragma unroll
    for (int i = 0; i < 4; ++i) {
      lsum[i] = lsum[i] * alpha[i] + psum[i];
      mrow[i] = newm[i];
    }
#pragma unroll
    for (int nt2 = 0; nt2 < 4; ++nt2)
#pragma unroll
      for (int i = 0; i < 4; ++i) o[nt2][i] *= alpha[i];

    short8 ap[4];
#pragma unroll
    for (int ks2 = 0; ks2 < 4; ++ks2)
      ap[ks2] = *(const short8*)&pbase[fr * PSTRIDE + ks2 * 32 + quad * 8];

    const __hip_bfloat16* vp =
        Vt + (size_t)(h * HDIM + fr) * SEQ + kb * BS + quad * 8;
#pragma unroll
    for (int nt2 = 0; nt2 < 4; ++nt2) {
      const __hip_bfloat16* vr = vp + (size_t)nt2 * 16 * SEQ;
#pragma unroll
      for (int ks2 = 0; ks2 < 4; ++ks2) {
        short8 vb = *(const short8*)(vr + ks2 * 32);
        o[nt2] = __builtin_amdgcn_mfma_f32_16x16x32_bf16(ap[ks2], vb, o[nt2], 0, 0, 0);
      }
    }
  }

  if (direct) {
    float inv[4];
#pragma unroll
    for (int i = 0; i < 4; ++i) inv[i] = 1.f / lsum[i];
#pragma unroll
    for (int nt2 = 0; nt2 < 4; ++nt2)
#pragma unroll
      for (int i = 0; i < 4; ++i)
        aout[(size_t)(q0 + wv * 16 + quad * 4 + i) * DIM + h * HDIM + nt2 * 16 + fr] =
            __float2bfloat16(o[nt2][i] * inv[i]);
  } else {
    float* pob = po + (size_t)pid * 4096 + (wv * 16 + quad * 4) * 64 + fr;
#pragma unroll
    for (int nt2 = 0; nt2 < 4; ++nt2)
#pragma unroll
      for (int i = 0; i < 4; ++i) pob[i * 64 + nt2 * 16] = o[nt2][i];
    if (fr == 0) {
#pragma unroll
      for (int i = 0; i < 4; ++i) {
        pm[pid * 64 + wv * 16 + quad * 4 + i] = mrow[i];
        pl[pid * 64 + wv * 16 + quad * 4 + i] = lsum[i];
      }
    }
  }
}

// ---------------------------------------------------------------------------
// Combine 8 KV-slice partials for the global q-blocks (unchanged).
// ---------------------------------------------------------------------------
__global__ __launch_bounds__(256) void combine(const float* __restrict__ po,
                                               const float* __restrict__ pm,
                                               const float* __restrict__ pl,
                                               __hip_bfloat16* __restrict__ aout) {
  int b = blockIdx.x;  // h*4 + chunk
  int h = b >> 2, chunk = b & 3;
  int t = threadIdx.x;
  int row = t >> 2;
  int d0 = (t & 3) * 16;

  float m8[8];
  float newm = -INFINITY;
#pragma unroll
  for (int s = 0; s < 8; ++s) {
    m8[s] = pm[(b * 8 + s) * 64 + row];
    newm = fmaxf(newm, m8[s]);
  }
  float wgt[8], lsum = 0.f;
#pragma unroll
  for (int s = 0; s < 8; ++s) {
    wgt[s] = __expf(m8[s] - newm);
    lsum += pl[(b * 8 + s) * 64 + row] * wgt[s];
  }
  float acc[16];
#pragma unroll
  for (int j = 0; j < 16; ++j) acc[j] = 0.f;
#pragma unroll
  for (int s = 0; s < 8; ++s) {
    const float* src = po + ((size_t)(b * 8 + s) * 4096) + row * 64 + d0;
#pragma unroll
    for (int j4 = 0; j4 < 4; ++j4) {
      float4 v = *(const float4*)(src + j4 * 4);
      acc[j4 * 4 + 0] += wgt[s] * v.x;
      acc[j4 * 4 + 1] += wgt[s] * v.y;
      acc[j4 * 4 + 2] += wgt[s] * v.z;
      acc[j4 * 4 + 3] += wgt[s] * v.w;
    }
  }
  float inv = 1.f / lsum;
  int qrow = (chunk >> 1) * 3072 + (chunk & 1) * 64 + row;
#pragma unroll
  for (int j = 0; j < 16; ++j)
    aout[(size_t)qrow * DIM + h * HDIM + d0 + j] = __float2bfloat16(acc[j] * inv);
}

// ---------------------------------------------------------------------------
extern "C" void kernel_launch(void* const* d_in, const int* in_sizes, int n_in,
                              void* d_out, int out_size, void* d_ws, size_t ws_size,
                              hipStream_t stream) {
  const float* x = (const float*)d_in[0];
  const float* w_qkv = (const float*)d_in[1];
  const float* b_qkv = (const float*)d_in[2];
  const float* w_out = (const float*)d_in[3];
  const float* b_out = (const float*)d_in[4];
  float* out = (float*)d_out;

  // ws layout (bytes):
  //   [0,   24M) bf16 qkv: Q[SEQ][DIM], K[SEQ][DIM], Vt[DIM][SEQ]
  //   [24M, 32M) bf16 x_bf   -- dead after gemm_qkv; reused as po (8MB fp32)
  //   [32M, 38M) bf16 wqkv_bf -- dead after gemm_qkv; first 256KB reused as pm/pl
  //   [38M, 40M) bf16 wout_bf
  //   [40M, 48M) bf16 attn_ws [SEQ][DIM]
  char* wsb = (char*)d_ws;
  __hip_bfloat16* qkv_ws = (__hip_bfloat16*)(wsb);
  __hip_bfloat16* x_bf = (__hip_bfloat16*)(wsb + 24ull * 1024 * 1024);
  __hip_bfloat16* wqkv_bf = (__hip_bfloat16*)(wsb + 32ull * 1024 * 1024);
  __hip_bfloat16* wout_bf = (__hip_bfloat16*)(wsb + 38ull * 1024 * 1024);
  __hip_bfloat16* attn_ws = (__hip_bfloat16*)(wsb + 40ull * 1024 * 1024);
  float* po = (float*)(wsb + 24ull * 1024 * 1024);           // 512*64*64*4 = 8MB
  float* pm = (float*)(wsb + 32ull * 1024 * 1024);           // 128KB
  float* pl = (float*)(wsb + 32ull * 1024 * 1024 + 131072);  // 128KB

  dim3 blk(256);
  downcast<<<dim3(SEQ * DIM / 1024), blk, 0, stream>>>(x, x_bf, SEQ * DIM);
  downcast<<<dim3(3 * DIM * DIM / 1024), blk, 0, stream>>>(w_qkv, wqkv_bf, 3 * DIM * DIM);
  downcast<<<dim3(DIM * DIM / 1024), blk, 0, stream>>>(w_out, wout_bf, DIM * DIM);
  gemm_qkv<<<dim3(3 * DIM / 128, SEQ / 128), blk, 0, stream>>>(x_bf, wqkv_bf, b_qkv, qkv_ws);
  attn_mfma<<<dim3(92, NHEADS), blk, 0, stream>>>(qkv_ws, attn_ws, po, pm, pl);
  combine<<<dim3(64), blk, 0, stream>>>(po, pm, pl, attn_ws);
  gemm_out<<<dim3(DIM / 128, SEQ / 128), blk, 0, stream>>>(attn_ws, wout_bf, b_out, out);
}

// Round 6
// 184.993 us; speedup vs baseline: 8.8404x; 1.2720x over previous
//
#include <hip/hip_runtime.h>
#include <hip/hip_bf16.h>
#include <math.h>

// BlockSparseAttention: x[1,4096,1024] fp32; w_qkv[3072,1024], b_qkv[3072],
// w_out[1024,1024], b_out[1024] fp32. out[4096,1024] fp32.
// blocks of 128; global blocks {0,24}; qb attends {0,qb,24} (or all if qb global).

#define SEQ 4096
#define DIM 1024
#define NHEADS 16
#define HDIM 64
#define BS 128
#define PSTRIDE 136   // 128 + 8 bf16 pad for attention P round-trip

using short8 = __attribute__((ext_vector_type(8))) short;   // 8 x bf16 bits
using floatx4 = __attribute__((ext_vector_type(4))) float;

__device__ __forceinline__ void gld_lds16(const __hip_bfloat16* g, __hip_bfloat16* l) {
  // 16B per lane, dest = wave-uniform base + lane*16 [guide §5, m97/m104]
  __builtin_amdgcn_global_load_lds(
      (const __attribute__((address_space(1))) unsigned int*)g,
      (__attribute__((address_space(3))) unsigned int*)l, 16, 0, 0);
}

// ---------------------------------------------------------------------------
// fp32 -> bf16 downcast
// ---------------------------------------------------------------------------
__global__ __launch_bounds__(256) void downcast(const float* __restrict__ src,
                                                __hip_bfloat16* __restrict__ dst,
                                                int n) {
  int i = (blockIdx.x * 256 + threadIdx.x) * 4;
  if (i >= n) return;
  float4 v = *(const float4*)(src + i);
  __hip_bfloat16 b0 = __float2bfloat16(v.x);
  __hip_bfloat16 b1 = __float2bfloat16(v.y);
  __hip_bfloat16 b2 = __float2bfloat16(v.z);
  __hip_bfloat16 b3 = __float2bfloat16(v.w);
  ushort4 packed = {*(unsigned short*)&b0, *(unsigned short*)&b1,
                    *(unsigned short*)&b2, *(unsigned short*)&b3};
  *(ushort4*)(((unsigned short*)dst) + i) = packed;
}

// ---------------------------------------------------------------------------
// m97-style 128x128 tiled GEMM (unchanged from round 5).
// ---------------------------------------------------------------------------
#define GEMM_MAIN_LOOP(Kd)                                                     \
  __shared__ __align__(16) __hip_bfloat16 Asmem[128 * 32];                     \
  __shared__ __align__(16) __hip_bfloat16 Bsmem[128 * 32];                     \
  const int t = threadIdx.x;                                                   \
  const int w = t >> 6;                                                        \
  const int lane = t & 63;                                                     \
  const int fr = lane & 15;                                                    \
  const int quad = lane >> 4;                                                  \
  const int wm = w >> 1, wn = w & 1;                                           \
  const int m0 = blockIdx.y * 128;                                             \
  const int n0 = blockIdx.x * 128;                                             \
  const __hip_bfloat16* Ablk = Amat + (size_t)m0 * Kd;                         \
  const __hip_bfloat16* Bblk = Wmat + (size_t)n0 * Kd;                         \
  floatx4 acc[4][4];                                                           \
  _Pragma("unroll") for (int i = 0; i < 4; ++i)                                \
      _Pragma("unroll") for (int j = 0; j < 4; ++j)                            \
          acc[i][j] = (floatx4){0.f, 0.f, 0.f, 0.f};                           \
  for (int kk = 0; kk < Kd / 32; ++kk) {                                       \
    _Pragma("unroll") for (int j = 0; j < 2; ++j) {                            \
      int c = j * 256 + t;                                                     \
      int ldso = (j * 256 + w * 64) * 8;                                       \
      gld_lds16(Ablk + (size_t)(c >> 2) * Kd + kk * 32 + (c & 3) * 8,          \
                &Asmem[ldso]);                                                 \
      gld_lds16(Bblk + (size_t)(c >> 2) * Kd + kk * 32 + (c & 3) * 8,          \
                &Bsmem[ldso]);                                                 \
    }                                                                          \
    __syncthreads();                                                           \
    short8 af[4], bf_[4];                                                      \
    _Pragma("unroll") for (int mt = 0; mt < 4; ++mt)                           \
        af[mt] = *(const short8*)&Asmem[(wm * 64 + mt * 16 + fr) * 32 + quad * 8]; \
    _Pragma("unroll") for (int nt = 0; nt < 4; ++nt)                           \
        bf_[nt] = *(const short8*)&Bsmem[(wn * 64 + nt * 16 + fr) * 32 + quad * 8]; \
    _Pragma("unroll") for (int mt = 0; mt < 4; ++mt)                           \
        _Pragma("unroll") for (int nt = 0; nt < 4; ++nt)                       \
            acc[mt][nt] = __builtin_amdgcn_mfma_f32_16x16x32_bf16(             \
                af[mt], bf_[nt], acc[mt][nt], 0, 0, 0);                        \
    __syncthreads();                                                           \
  }

// QKV: writes Q,K row-major bf16; V transposed (Vt[dim][seq]).
__global__ __launch_bounds__(256) void gemm_qkv(const __hip_bfloat16* __restrict__ Amat,
                                                const __hip_bfloat16* __restrict__ Wmat,
                                                const float* __restrict__ Bias,
                                                __hip_bfloat16* __restrict__ qkv) {
  GEMM_MAIN_LOOP(DIM)
  __hip_bfloat16* vt = qkv + 2ull * SEQ * DIM;
#pragma unroll
  for (int nt = 0; nt < 4; ++nt) {
    int n = n0 + wn * 64 + nt * 16 + fr;
    float bv = Bias[n];
    int s = n >> 10;          // uniform within a 16-col tile (never crosses 1024)
    int cc = n & 1023;
#pragma unroll
    for (int mt = 0; mt < 4; ++mt) {
      int m = m0 + wm * 64 + mt * 16 + quad * 4;
      if (s == 2) {
        ushort4 pk;
        unsigned short* pks = (unsigned short*)&pk;
#pragma unroll
        for (int i = 0; i < 4; ++i) {
          __hip_bfloat16 bb = __float2bfloat16(acc[mt][nt][i] + bv);
          pks[i] = *(unsigned short*)&bb;
        }
        *(ushort4*)(vt + (size_t)cc * SEQ + m) = pk;
      } else {
        __hip_bfloat16* dst = qkv + (size_t)s * SEQ * DIM + cc;
#pragma unroll
        for (int i = 0; i < 4; ++i)
          dst[(size_t)(m + i) * DIM] = __float2bfloat16(acc[mt][nt][i] + bv);
      }
    }
  }
}

__global__ __launch_bounds__(256) void gemm_out(const __hip_bfloat16* __restrict__ Amat,
                                                const __hip_bfloat16* __restrict__ Wmat,
                                                const float* __restrict__ Bias,
                                                float* __restrict__ out) {
  GEMM_MAIN_LOOP(DIM)
#pragma unroll
  for (int nt = 0; nt < 4; ++nt) {
    int n = n0 + wn * 64 + nt * 16 + fr;
    float bv = Bias[n];
#pragma unroll
    for (int mt = 0; mt < 4; ++mt) {
      int m = m0 + wm * 64 + mt * 16 + quad * 4;
#pragma unroll
      for (int i = 0; i < 4; ++i)
        out[(size_t)(m + i) * DIM + n] = acc[mt][nt][i] + bv;
    }
  }
}

// ---------------------------------------------------------------------------
// MFMA flash attention with KV-split + cooperative frag-major LDS staging.
// Grid: (92, 16heads) x 256 thr. Wave wv owns q-rows [q0+wv*16, +16).
// Per KV block: the WG stages K (16KB) and V (16KB) tiles into LDS in
// FRAGMENT-MAJOR layout (frag f = 1KB at f*1024, slot = lane*16B) via
// global_load_lds; all 4 waves then read conflict-free ds_read_b128 frags.
//   K frag f = nt*2+ks  : lane holds K[key=nt*16+fr][dim=ks*32+quad*8..+7]
//   V frag f = nt2*4+ks2: lane holds V[dim=nt2*16+fr][key=ks2*32+quad*8..+7]
// Softmax + P round-trip are wave-local (no barrier); 2 barriers per block.
// ---------------------------------------------------------------------------
__global__ __launch_bounds__(256) void attn_mfma(
    const __hip_bfloat16* __restrict__ qkv,
    __hip_bfloat16* __restrict__ aout,
    float* __restrict__ po, float* __restrict__ pm, float* __restrict__ pl) {
  __shared__ __align__(16) __hip_bfloat16 Kbuf[16 * 512];    // 16KB, 16 frags
  __shared__ __align__(16) __hip_bfloat16 Vbuf[16 * 512];    // 16KB, 16 frags
  __shared__ __hip_bfloat16 p_lds[4 * 16 * PSTRIDE];         // 17408 B
  const int h = blockIdx.y;
  const int wgid = blockIdx.x;
  const int t = threadIdx.x;
  const int wv = t >> 6;
  const int lane = t & 63;
  const int fr = lane & 15;
  const int quad = lane >> 4;

  int qb, q0, niter, slice = 0, pid = 0;
  bool direct;
  if (wgid < 60) {
    int nb = wgid >> 1;                 // 0..29
    qb = (nb < 23) ? nb + 1 : nb + 2;   // 1..23, 25..31
    q0 = qb * BS + (wgid & 1) * 64;
    niter = 3;
    direct = true;
  } else {
    int gi = wgid - 60;                 // 0..31
    slice = gi & 7;
    int chunk = gi >> 3;                // 0..3
    qb = (chunk >> 1) * 24;             // 0 or 24
    q0 = qb * BS + (chunk & 1) * 64;
    niter = 4;
    direct = false;
    pid = (h * 4 + chunk) * 8 + slice;
  }

  const __hip_bfloat16* Q = qkv;
  const __hip_bfloat16* K = qkv + (size_t)SEQ * DIM;
  const __hip_bfloat16* Vt = qkv + 2ull * SEQ * DIM;  // [DIM][SEQ]

  short8 qa0, qa1;
  {
    const __hip_bfloat16* qp =
        Q + (size_t)(q0 + wv * 16 + fr) * DIM + h * HDIM + quad * 8;
    qa0 = *(const short8*)(qp);
    qa1 = *(const short8*)(qp + 32);
  }

  float mrow[4] = {-INFINITY, -INFINITY, -INFINITY, -INFINITY};
  float lsum[4] = {0.f, 0.f, 0.f, 0.f};
  floatx4 o[4];
#pragma unroll
  for (int i = 0; i < 4; ++i) o[i] = (floatx4){0.f, 0.f, 0.f, 0.f};

  __hip_bfloat16* pbase = &p_lds[wv * 16 * PSTRIDE];

  for (int bi = 0; bi < niter; ++bi) {
    int kb = direct ? (bi == 0 ? 0 : (bi == 1 ? qb : 24)) : slice * 4 + bi;

    // ---- cooperative frag-major staging of K and V tiles ----
    const __hip_bfloat16* Kg = K + (size_t)(kb * BS) * DIM + h * HDIM;
    const __hip_bfloat16* Vg = Vt + (size_t)(h * HDIM) * SEQ + kb * BS;
    __syncthreads();  // all waves done reading previous K/V tiles
#pragma unroll
    for (int rr = 0; rr < 4; ++rr) {
      int f = rr * 4 + wv;              // wave-uniform frag id
      int nt = f >> 1, ks = f & 1;      // K frag coords
      gld_lds16(Kg + (size_t)(nt * 16 + fr) * DIM + ks * 32 + quad * 8,
                &Kbuf[f * 512]);
      int nt2 = f >> 2, ks2 = f & 3;    // V frag coords
      gld_lds16(Vg + (size_t)(nt2 * 16 + fr) * SEQ + ks2 * 32 + quad * 8,
                &Vbuf[f * 512]);
    }
    __syncthreads();  // DMA drained (vmcnt(0) before barrier)

    // ---- QK^T from LDS frags ----
    floatx4 s[8];
#pragma unroll
    for (int nt = 0; nt < 8; ++nt) {
      short8 kf0 = *(const short8*)&Kbuf[(nt * 2 + 0) * 512 + lane * 8];
      short8 kf1 = *(const short8*)&Kbuf[(nt * 2 + 1) * 512 + lane * 8];
      floatx4 acc = {0.f, 0.f, 0.f, 0.f};
      acc = __builtin_amdgcn_mfma_f32_16x16x32_bf16(qa0, kf0, acc, 0, 0, 0);
      acc = __builtin_amdgcn_mfma_f32_16x16x32_bf16(qa1, kf1, acc, 0, 0, 0);
      s[nt] = acc;
    }
#pragma unroll
    for (int nt = 0; nt < 8; ++nt)
#pragma unroll
      for (int i = 0; i < 4; ++i) s[nt][i] *= 0.125f;

    // ---- in-wave online softmax ----
    float rmax[4];
#pragma unroll
    for (int i = 0; i < 4; ++i) {
      float m = s[0][i];
#pragma unroll
      for (int nt = 1; nt < 8; ++nt) m = fmaxf(m, s[nt][i]);
      rmax[i] = m;
    }
#pragma unroll
    for (int off = 1; off < 16; off <<= 1)
#pragma unroll
      for (int i = 0; i < 4; ++i)
        rmax[i] = fmaxf(rmax[i], __shfl_xor(rmax[i], off, 64));

    float newm[4], alpha[4], psum[4];
#pragma unroll
    for (int i = 0; i < 4; ++i) {
      newm[i] = fmaxf(mrow[i], rmax[i]);
      alpha[i] = __expf(mrow[i] - newm[i]);
      psum[i] = 0.f;
    }
#pragma unroll
    for (int nt = 0; nt < 8; ++nt)
#pragma unroll
      for (int i = 0; i < 4; ++i) {
        float p = __expf(s[nt][i] - newm[i]);
        psum[i] += p;
        __hip_bfloat16 pb = __float2bfloat16(p);
        pbase[(quad * 4 + i) * PSTRIDE + nt * 16 + fr] = pb;
      }
#pragma unroll
    for (int off = 1; off < 16; off <<= 1)
#pragma unroll
      for (int i = 0; i < 4; ++i) psum[i] += __shfl_xor(psum[i], off, 64);
#pragma unroll
    for (int i = 0; i < 4; ++i) {
      lsum[i] = lsum[i] * alpha[i] + psum[i];
      mrow[i] = newm[i];
    }
#pragma unroll
    for (int nt2 = 0; nt2 < 4; ++nt2)
#pragma unroll
      for (int i = 0; i < 4; ++i) o[nt2][i] *= alpha[i];

    // ---- P A-frags (wave-local RAW; compiler inserts lgkmcnt) ----
    short8 ap[4];
#pragma unroll
    for (int ks2 = 0; ks2 < 4; ++ks2)
      ap[ks2] = *(const short8*)&pbase[fr * PSTRIDE + ks2 * 32 + quad * 8];

    // ---- PV from LDS V frags ----
#pragma unroll
    for (int nt2 = 0; nt2 < 4; ++nt2) {
#pragma unroll
      for (int ks2 = 0; ks2 < 4; ++ks2) {
        short8 vb = *(const short8*)&Vbuf[(nt2 * 4 + ks2) * 512 + lane * 8];
        o[nt2] = __builtin_amdgcn_mfma_f32_16x16x32_bf16(ap[ks2], vb, o[nt2], 0, 0, 0);
      }
    }
  }

  if (direct) {
    float inv[4];
#pragma unroll
    for (int i = 0; i < 4; ++i) inv[i] = 1.f / lsum[i];
#pragma unroll
    for (int nt2 = 0; nt2 < 4; ++nt2)
#pragma unroll
      for (int i = 0; i < 4; ++i)
        aout[(size_t)(q0 + wv * 16 + quad * 4 + i) * DIM + h * HDIM + nt2 * 16 + fr] =
            __float2bfloat16(o[nt2][i] * inv[i]);
  } else {
    float* pob = po + (size_t)pid * 4096 + (wv * 16 + quad * 4) * 64 + fr;
#pragma unroll
    for (int nt2 = 0; nt2 < 4; ++nt2)
#pragma unroll
      for (int i = 0; i < 4; ++i) pob[i * 64 + nt2 * 16] = o[nt2][i];
    if (fr == 0) {
#pragma unroll
      for (int i = 0; i < 4; ++i) {
        pm[pid * 64 + wv * 16 + quad * 4 + i] = mrow[i];
        pl[pid * 64 + wv * 16 + quad * 4 + i] = lsum[i];
      }
    }
  }
}

// ---------------------------------------------------------------------------
// Combine 8 KV-slice partials for the global q-blocks (unchanged).
// ---------------------------------------------------------------------------
__global__ __launch_bounds__(256) void combine(const float* __restrict__ po,
                                               const float* __restrict__ pm,
                                               const float* __restrict__ pl,
                                               __hip_bfloat16* __restrict__ aout) {
  int b = blockIdx.x;  // h*4 + chunk
  int h = b >> 2, chunk = b & 3;
  int t = threadIdx.x;
  int row = t >> 2;
  int d0 = (t & 3) * 16;

  float m8[8];
  float newm = -INFINITY;
#pragma unroll
  for (int s = 0; s < 8; ++s) {
    m8[s] = pm[(b * 8 + s) * 64 + row];
    newm = fmaxf(newm, m8[s]);
  }
  float wgt[8], lsum = 0.f;
#pragma unroll
  for (int s = 0; s < 8; ++s) {
    wgt[s] = __expf(m8[s] - newm);
    lsum += pl[(b * 8 + s) * 64 + row] * wgt[s];
  }
  float acc[16];
#pragma unroll
  for (int j = 0; j < 16; ++j) acc[j] = 0.f;
#pragma unroll
  for (int s = 0; s < 8; ++s) {
    const float* src = po + ((size_t)(b * 8 + s) * 4096) + row * 64 + d0;
#pragma unroll
    for (int j4 = 0; j4 < 4; ++j4) {
      float4 v = *(const float4*)(src + j4 * 4);
      acc[j4 * 4 + 0] += wgt[s] * v.x;
      acc[j4 * 4 + 1] += wgt[s] * v.y;
      acc[j4 * 4 + 2] += wgt[s] * v.z;
      acc[j4 * 4 + 3] += wgt[s] * v.w;
    }
  }
  float inv = 1.f / lsum;
  int qrow = (chunk >> 1) * 3072 + (chunk & 1) * 64 + row;
#pragma unroll
  for (int j = 0; j < 16; ++j)
    aout[(size_t)qrow * DIM + h * HDIM + d0 + j] = __float2bfloat16(acc[j] * inv);
}

// ---------------------------------------------------------------------------
extern "C" void kernel_launch(void* const* d_in, const int* in_sizes, int n_in,
                              void* d_out, int out_size, void* d_ws, size_t ws_size,
                              hipStream_t stream) {
  const float* x = (const float*)d_in[0];
  const float* w_qkv = (const float*)d_in[1];
  const float* b_qkv = (const float*)d_in[2];
  const float* w_out = (const float*)d_in[3];
  const float* b_out = (const float*)d_in[4];
  float* out = (float*)d_out;

  // ws layout (bytes):
  //   [0,   24M) bf16 qkv: Q[SEQ][DIM], K[SEQ][DIM], Vt[DIM][SEQ]
  //   [24M, 32M) bf16 x_bf   -- dead after gemm_qkv; reused as po (8MB fp32)
  //   [32M, 38M) bf16 wqkv_bf -- dead after gemm_qkv; first 256KB reused as pm/pl
  //   [38M, 40M) bf16 wout_bf
  //   [40M, 48M) bf16 attn_ws [SEQ][DIM]
  char* wsb = (char*)d_ws;
  __hip_bfloat16* qkv_ws = (__hip_bfloat16*)(wsb);
  __hip_bfloat16* x_bf = (__hip_bfloat16*)(wsb + 24ull * 1024 * 1024);
  __hip_bfloat16* wqkv_bf = (__hip_bfloat16*)(wsb + 32ull * 1024 * 1024);
  __hip_bfloat16* wout_bf = (__hip_bfloat16*)(wsb + 38ull * 1024 * 1024);
  __hip_bfloat16* attn_ws = (__hip_bfloat16*)(wsb + 40ull * 1024 * 1024);
  float* po = (float*)(wsb + 24ull * 1024 * 1024);           // 512*64*64*4 = 8MB
  float* pm = (float*)(wsb + 32ull * 1024 * 1024);           // 128KB
  float* pl = (float*)(wsb + 32ull * 1024 * 1024 + 131072);  // 128KB

  dim3 blk(256);
  downcast<<<dim3(SEQ * DIM / 1024), blk, 0, stream>>>(x, x_bf, SEQ * DIM);
  downcast<<<dim3(3 * DIM * DIM / 1024), blk, 0, stream>>>(w_qkv, wqkv_bf, 3 * DIM * DIM);
  downcast<<<dim3(DIM * DIM / 1024), blk, 0, stream>>>(w_out, wout_bf, DIM * DIM);
  gemm_qkv<<<dim3(3 * DIM / 128, SEQ / 128), blk, 0, stream>>>(x_bf, wqkv_bf, b_qkv, qkv_ws);
  attn_mfma<<<dim3(92, NHEADS), blk, 0, stream>>>(qkv_ws, attn_ws, po, pm, pl);
  combine<<<dim3(64), blk, 0, stream>>>(po, pm, pl, attn_ws);
  gemm_out<<<dim3(DIM / 128, SEQ / 128), blk, 0, stream>>>(attn_ws, wout_bf, b_out, out);
}

// Round 7
// 178.058 us; speedup vs baseline: 9.1847x; 1.0389x over previous
//
#include <hip/hip_runtime.h>
#include <hip/hip_bf16.h>
#include <math.h>

// BlockSparseAttention: x[1,4096,1024] fp32; w_qkv[3072,1024], b_qkv[3072],
// w_out[1024,1024], b_out[1024] fp32. out[4096,1024] fp32.
// blocks of 128; global blocks {0,24}; qb attends {0,qb,24} (or all if qb global).

#define SEQ 4096
#define DIM 1024
#define NHEADS 16
#define HDIM 64
#define BS 128
#define PSTRIDE 136   // attention P round-trip pad
#define ESTRIDE 136   // gemm epilogue staging pad (136*2B = 272B rows, 16B-aligned)

using short8 = __attribute__((ext_vector_type(8))) short;   // 8 x bf16 bits
using floatx4 = __attribute__((ext_vector_type(4))) float;

__device__ __forceinline__ float bf2f(short s) {
  unsigned u = ((unsigned)(unsigned short)s) << 16;
  return __uint_as_float(u);
}

__device__ __forceinline__ void gld_lds16(const __hip_bfloat16* g, __hip_bfloat16* l) {
  // 16B per lane, dest = wave-uniform base + lane*16 [guide §5, m97/m104]
  __builtin_amdgcn_global_load_lds(
      (const __attribute__((address_space(1))) unsigned int*)g,
      (__attribute__((address_space(3))) unsigned int*)l, 16, 0, 0);
}

// ---------------------------------------------------------------------------
// merged fp32 -> bf16 downcast for x (4096 blks), w_qkv (3072), w_out (1024)
// ---------------------------------------------------------------------------
__global__ __launch_bounds__(256) void downcast3(
    const float* __restrict__ x, const float* __restrict__ wq,
    const float* __restrict__ wo, __hip_bfloat16* __restrict__ xd,
    __hip_bfloat16* __restrict__ wqd, __hip_bfloat16* __restrict__ wod) {
  int id = blockIdx.x;
  const float* src;
  __hip_bfloat16* dst;
  int base;
  if (id < 4096) { src = x; dst = xd; base = id; }
  else if (id < 7168) { src = wq; dst = wqd; base = id - 4096; }
  else { src = wo; dst = wod; base = id - 7168; }
  int i = (base * 256 + threadIdx.x) * 4;
  float4 v = *(const float4*)(src + i);
  __hip_bfloat16 b0 = __float2bfloat16(v.x);
  __hip_bfloat16 b1 = __float2bfloat16(v.y);
  __hip_bfloat16 b2 = __float2bfloat16(v.z);
  __hip_bfloat16 b3 = __float2bfloat16(v.w);
  ushort4 packed = {*(unsigned short*)&b0, *(unsigned short*)&b1,
                    *(unsigned short*)&b2, *(unsigned short*)&b3};
  *(ushort4*)(((unsigned short*)dst) + i) = packed;
}

// ---------------------------------------------------------------------------
// QKV GEMM, m97 structure + LDS-staged coalesced epilogue.
// 1D grid 768 = 32 m-tiles x 24 n-tiles, XCD-swizzled (4 m x 24 n per XCD).
// Operand roles depend on output stream (s = n0>>10, wg-uniform):
//   s<2 (Q,K): A-op = W rows, B-op = X rows  -> D[n][m]
//   s=2 (V)  : A-op = X rows, B-op = W rows  -> D[m][n]
// Unified staging Ep[dcol*136 + drow] (dcol = D-col = B-op row, drow = D-row)
// makes each thread's 4 i-values contiguous (ds_write_b64 x16), and read-back
// rows map to full 256B cache-line-aligned global stores for both layouts.
// ---------------------------------------------------------------------------
__global__ __launch_bounds__(256) void gemm_qkv(const __hip_bfloat16* __restrict__ Amat,
                                                const __hip_bfloat16* __restrict__ Wmat,
                                                const float* __restrict__ Bias,
                                                __hip_bfloat16* __restrict__ qkv) {
  __shared__ __align__(16) char pool[128 * ESTRIDE * 2];  // 34816 B
  __hip_bfloat16* Asmem = (__hip_bfloat16*)pool;          // 8KB during K-loop
  __hip_bfloat16* Bsmem = (__hip_bfloat16*)(pool + 8192); // 8KB during K-loop
  __hip_bfloat16* Ep = (__hip_bfloat16*)pool;             // 34KB epilogue

  const int Kd = DIM;
  const int t = threadIdx.x;
  const int w = t >> 6;
  const int lane = t & 63;
  const int fr = lane & 15;
  const int quad = lane >> 4;
  const int wm = w >> 1, wn = w & 1;

  // XCD swizzle: same-m0 workgroups share an XCD for L2 x-slab reuse
  int id = blockIdx.x;
  int xcd = id & 7, j = id >> 3;       // j in [0,96)
  int m_idx = xcd + (j & 3) * 8;       // {xcd, xcd+8, xcd+16, xcd+24}
  int n_idx = j >> 2;                  // 0..23
  const int m0 = m_idx * 128;
  const int n0 = n_idx * 128;
  const int s = n0 >> 10;              // 0=Q,1=K,2=V (wg-uniform)
  const int cc0 = n0 & 1023;
  const bool vmode = (s == 2);

  const __hip_bfloat16* APtr = vmode ? Amat + (size_t)m0 * Kd : Wmat + (size_t)n0 * Kd;
  const __hip_bfloat16* BPtr = vmode ? Wmat + (size_t)n0 * Kd : Amat + (size_t)m0 * Kd;

  floatx4 acc[4][4];
#pragma unroll
  for (int i = 0; i < 4; ++i)
#pragma unroll
    for (int jj = 0; jj < 4; ++jj) acc[i][jj] = (floatx4){0.f, 0.f, 0.f, 0.f};

  for (int kk = 0; kk < Kd / 32; ++kk) {
#pragma unroll
    for (int jj = 0; jj < 2; ++jj) {
      int c = jj * 256 + t;
      int ldso = (jj * 256 + w * 64) * 8;
      gld_lds16(APtr + (size_t)(c >> 2) * Kd + kk * 32 + (c & 3) * 8, &Asmem[ldso]);
      gld_lds16(BPtr + (size_t)(c >> 2) * Kd + kk * 32 + (c & 3) * 8, &Bsmem[ldso]);
    }
    __syncthreads();
    short8 af[4], bf_[4];
#pragma unroll
    for (int mt = 0; mt < 4; ++mt)
      af[mt] = *(const short8*)&Asmem[(wm * 64 + mt * 16 + fr) * 32 + quad * 8];
#pragma unroll
    for (int nt = 0; nt < 4; ++nt)
      bf_[nt] = *(const short8*)&Bsmem[(wn * 64 + nt * 16 + fr) * 32 + quad * 8];
#pragma unroll
    for (int mt = 0; mt < 4; ++mt)
#pragma unroll
      for (int nt = 0; nt < 4; ++nt)
        acc[mt][nt] = __builtin_amdgcn_mfma_f32_16x16x32_bf16(af[mt], bf_[nt],
                                                              acc[mt][nt], 0, 0, 0);
    __syncthreads();
  }

  // ---- stage D into Ep[dcol*136 + drow]: i-contiguous ds_write_b64 ----
#pragma unroll
  for (int nt = 0; nt < 4; ++nt) {
    int dcol = wn * 64 + nt * 16 + fr;
#pragma unroll
    for (int mt = 0; mt < 4; ++mt) {
      int drow0 = wm * 64 + mt * 16 + quad * 4;
      ushort4 pk;
      unsigned short* pks = (unsigned short*)&pk;
#pragma unroll
      for (int i = 0; i < 4; ++i) {
        __hip_bfloat16 bb = __float2bfloat16(acc[mt][nt][i]);
        pks[i] = *(unsigned short*)&bb;
      }
      *(ushort4*)&Ep[dcol * ESTRIDE + drow0] = pk;
    }
  }
  __syncthreads();

  // ---- coalesced read-back + bias + 16B global stores ----
  if (!vmode) {
    // Ep rows = m (0..127), cols = n-local; store qkv[s][m0+m][cc0..+127]
    __hip_bfloat16* dst = qkv + (size_t)s * SEQ * DIM;
#pragma unroll
    for (int rr = 0; rr < 8; ++rr) {
      int m = rr * 16 + (t >> 4);
      int ch = (t & 15) * 8;
      short8 v8 = *(const short8*)&Ep[m * ESTRIDE + ch];
      float4 b0 = *(const float4*)&Bias[n0 + ch];
      float4 b1 = *(const float4*)&Bias[n0 + ch + 4];
      float bb[8] = {b0.x, b0.y, b0.z, b0.w, b1.x, b1.y, b1.z, b1.w};
      short8 o8;
#pragma unroll
      for (int k = 0; k < 8; ++k) {
        __hip_bfloat16 ob = __float2bfloat16(bf2f(v8[k]) + bb[k]);
        o8[k] = *(short*)&ob;
      }
      *(short8*)&dst[(size_t)(m0 + m) * DIM + cc0 + ch] = o8;
    }
  } else {
    // Ep rows = n-local, cols = m; store Vt[(cc0+n)][m0..+127]
    __hip_bfloat16* vt = qkv + 2ull * SEQ * DIM;
#pragma unroll
    for (int rr = 0; rr < 8; ++rr) {
      int nrow = rr * 16 + (t >> 4);
      int ch = (t & 15) * 8;
      float bv = Bias[n0 + nrow];
      short8 v8 = *(const short8*)&Ep[nrow * ESTRIDE + ch];
      short8 o8;
#pragma unroll
      for (int k = 0; k < 8; ++k) {
        __hip_bfloat16 ob = __float2bfloat16(bf2f(v8[k]) + bv);
        o8[k] = *(short*)&ob;
      }
      *(short8*)&vt[(size_t)(cc0 + nrow) * SEQ + m0 + ch] = o8;
    }
  }
}

// ---------------------------------------------------------------------------
// out-proj GEMM: m97 structure, fp32 epilogue already full-line coalesced.
// 1D grid 256 = 32 m-tiles x 8 n-tiles, XCD-swizzled.
// ---------------------------------------------------------------------------
__global__ __launch_bounds__(256) void gemm_out(const __hip_bfloat16* __restrict__ Amat,
                                                const __hip_bfloat16* __restrict__ Wmat,
                                                const float* __restrict__ Bias,
                                                float* __restrict__ out) {
  __shared__ __align__(16) __hip_bfloat16 Asmem[128 * 32];
  __shared__ __align__(16) __hip_bfloat16 Bsmem[128 * 32];
  const int Kd = DIM;
  const int t = threadIdx.x;
  const int w = t >> 6;
  const int lane = t & 63;
  const int fr = lane & 15;
  const int quad = lane >> 4;
  const int wm = w >> 1, wn = w & 1;
  int id = blockIdx.x;
  int xcd = id & 7, j = id >> 3;       // j in [0,32)
  int m_idx = xcd + (j & 3) * 8;
  int n_idx = j >> 2;                  // 0..7
  const int m0 = m_idx * 128;
  const int n0 = n_idx * 128;
  const __hip_bfloat16* Ablk = Amat + (size_t)m0 * Kd;
  const __hip_bfloat16* Bblk = Wmat + (size_t)n0 * Kd;
  floatx4 acc[4][4];
#pragma unroll
  for (int i = 0; i < 4; ++i)
#pragma unroll
    for (int jj = 0; jj < 4; ++jj) acc[i][jj] = (floatx4){0.f, 0.f, 0.f, 0.f};
  for (int kk = 0; kk < Kd / 32; ++kk) {
#pragma unroll
    for (int jj = 0; jj < 2; ++jj) {
      int c = jj * 256 + t;
      int ldso = (jj * 256 + w * 64) * 8;
      gld_lds16(Ablk + (size_t)(c >> 2) * Kd + kk * 32 + (c & 3) * 8, &Asmem[ldso]);
      gld_lds16(Bblk + (size_t)(c >> 2) * Kd + kk * 32 + (c & 3) * 8, &Bsmem[ldso]);
    }
    __syncthreads();
    short8 af[4], bf_[4];
#pragma unroll
    for (int mt = 0; mt < 4; ++mt)
      af[mt] = *(const short8*)&Asmem[(wm * 64 + mt * 16 + fr) * 32 + quad * 8];
#pragma unroll
    for (int nt = 0; nt < 4; ++nt)
      bf_[nt] = *(const short8*)&Bsmem[(wn * 64 + nt * 16 + fr) * 32 + quad * 8];
#pragma unroll
    for (int mt = 0; mt < 4; ++mt)
#pragma unroll
      for (int nt = 0; nt < 4; ++nt)
        acc[mt][nt] = __builtin_amdgcn_mfma_f32_16x16x32_bf16(af[mt], bf_[nt],
                                                              acc[mt][nt], 0, 0, 0);
    __syncthreads();
  }
#pragma unroll
  for (int nt = 0; nt < 4; ++nt) {
    int n = n0 + wn * 64 + nt * 16 + fr;
    float bv = Bias[n];
#pragma unroll
    for (int mt = 0; mt < 4; ++mt) {
      int m = m0 + wm * 64 + mt * 16 + quad * 4;
#pragma unroll
      for (int i = 0; i < 4; ++i)
        out[(size_t)(m + i) * DIM + n] = acc[mt][nt][i] + bv;
    }
  }
}

// ---------------------------------------------------------------------------
// MFMA flash attention with KV-split + cooperative frag-major LDS staging
// (unchanged from round 6).
// ---------------------------------------------------------------------------
__global__ __launch_bounds__(256) void attn_mfma(
    const __hip_bfloat16* __restrict__ qkv,
    __hip_bfloat16* __restrict__ aout,
    float* __restrict__ po, float* __restrict__ pm, float* __restrict__ pl) {
  __shared__ __align__(16) __hip_bfloat16 Kbuf[16 * 512];    // 16KB, 16 frags
  __shared__ __align__(16) __hip_bfloat16 Vbuf[16 * 512];    // 16KB, 16 frags
  __shared__ __hip_bfloat16 p_lds[4 * 16 * PSTRIDE];         // 17408 B
  const int h = blockIdx.y;
  const int wgid = blockIdx.x;
  const int t = threadIdx.x;
  const int wv = t >> 6;
  const int lane = t & 63;
  const int fr = lane & 15;
  const int quad = lane >> 4;

  int qb, q0, niter, slice = 0, pid = 0;
  bool direct;
  if (wgid < 60) {
    int nb = wgid >> 1;                 // 0..29
    qb = (nb < 23) ? nb + 1 : nb + 2;   // 1..23, 25..31
    q0 = qb * BS + (wgid & 1) * 64;
    niter = 3;
    direct = true;
  } else {
    int gi = wgid - 60;                 // 0..31
    slice = gi & 7;
    int chunk = gi >> 3;                // 0..3
    qb = (chunk >> 1) * 24;             // 0 or 24
    q0 = qb * BS + (chunk & 1) * 64;
    niter = 4;
    direct = false;
    pid = (h * 4 + chunk) * 8 + slice;
  }

  const __hip_bfloat16* Q = qkv;
  const __hip_bfloat16* K = qkv + (size_t)SEQ * DIM;
  const __hip_bfloat16* Vt = qkv + 2ull * SEQ * DIM;  // [DIM][SEQ]

  short8 qa0, qa1;
  {
    const __hip_bfloat16* qp =
        Q + (size_t)(q0 + wv * 16 + fr) * DIM + h * HDIM + quad * 8;
    qa0 = *(const short8*)(qp);
    qa1 = *(const short8*)(qp + 32);
  }

  float mrow[4] = {-INFINITY, -INFINITY, -INFINITY, -INFINITY};
  float lsum[4] = {0.f, 0.f, 0.f, 0.f};
  floatx4 o[4];
#pragma unroll
  for (int i = 0; i < 4; ++i) o[i] = (floatx4){0.f, 0.f, 0.f, 0.f};

  __hip_bfloat16* pbase = &p_lds[wv * 16 * PSTRIDE];

  for (int bi = 0; bi < niter; ++bi) {
    int kb = direct ? (bi == 0 ? 0 : (bi == 1 ? qb : 24)) : slice * 4 + bi;

    // ---- cooperative frag-major staging of K and V tiles ----
    const __hip_bfloat16* Kg = K + (size_t)(kb * BS) * DIM + h * HDIM;
    const __hip_bfloat16* Vg = Vt + (size_t)(h * HDIM) * SEQ + kb * BS;
    __syncthreads();  // all waves done reading previous K/V tiles
#pragma unroll
    for (int rr = 0; rr < 4; ++rr) {
      int f = rr * 4 + wv;              // wave-uniform frag id
      int nt = f >> 1, ks = f & 1;      // K frag coords
      gld_lds16(Kg + (size_t)(nt * 16 + fr) * DIM + ks * 32 + quad * 8,
                &Kbuf[f * 512]);
      int nt2 = f >> 2, ks2 = f & 3;    // V frag coords
      gld_lds16(Vg + (size_t)(nt2 * 16 + fr) * SEQ + ks2 * 32 + quad * 8,
                &Vbuf[f * 512]);
    }
    __syncthreads();  // DMA drained (vmcnt(0) before barrier)

    // ---- QK^T from LDS frags ----
    floatx4 s[8];
#pragma unroll
    for (int nt = 0; nt < 8; ++nt) {
      short8 kf0 = *(const short8*)&Kbuf[(nt * 2 + 0) * 512 + lane * 8];
      short8 kf1 = *(const short8*)&Kbuf[(nt * 2 + 1) * 512 + lane * 8];
      floatx4 acc = {0.f, 0.f, 0.f, 0.f};
      acc = __builtin_amdgcn_mfma_f32_16x16x32_bf16(qa0, kf0, acc, 0, 0, 0);
      acc = __builtin_amdgcn_mfma_f32_16x16x32_bf16(qa1, kf1, acc, 0, 0, 0);
      s[nt] = acc;
    }
#pragma unroll
    for (int nt = 0; nt < 8; ++nt)
#pragma unroll
      for (int i = 0; i < 4; ++i) s[nt][i] *= 0.125f;

    // ---- in-wave online softmax ----
    float rmax[4];
#pragma unroll
    for (int i = 0; i < 4; ++i) {
      float m = s[0][i];
#pragma unroll
      for (int nt = 1; nt < 8; ++nt) m = fmaxf(m, s[nt][i]);
      rmax[i] = m;
    }
#pragma unroll
    for (int off = 1; off < 16; off <<= 1)
#pragma unroll
      for (int i = 0; i < 4; ++i)
        rmax[i] = fmaxf(rmax[i], __shfl_xor(rmax[i], off, 64));

    float newm[4], alpha[4], psum[4];
#pragma unroll
    for (int i = 0; i < 4; ++i) {
      newm[i] = fmaxf(mrow[i], rmax[i]);
      alpha[i] = __expf(mrow[i] - newm[i]);
      psum[i] = 0.f;
    }
#pragma unroll
    for (int nt = 0; nt < 8; ++nt)
#pragma unroll
      for (int i = 0; i < 4; ++i) {
        float p = __expf(s[nt][i] - newm[i]);
        psum[i] += p;
        __hip_bfloat16 pb = __float2bfloat16(p);
        pbase[(quad * 4 + i) * PSTRIDE + nt * 16 + fr] = pb;
      }
#pragma unroll
    for (int off = 1; off < 16; off <<= 1)
#pragma unroll
      for (int i = 0; i < 4; ++i) psum[i] += __shfl_xor(psum[i], off, 64);
#pragma unroll
    for (int i = 0; i < 4; ++i) {
      lsum[i] = lsum[i] * alpha[i] + psum[i];
      mrow[i] = newm[i];
    }
#pragma unroll
    for (int nt2 = 0; nt2 < 4; ++nt2)
#pragma unroll
      for (int i = 0; i < 4; ++i) o[nt2][i] *= alpha[i];

    // ---- P A-frags (wave-local RAW; compiler inserts lgkmcnt) ----
    short8 ap[4];
#pragma unroll
    for (int ks2 = 0; ks2 < 4; ++ks2)
      ap[ks2] = *(const short8*)&pbase[fr * PSTRIDE + ks2 * 32 + quad * 8];

    // ---- PV from LDS V frags ----
#pragma unroll
    for (int nt2 = 0; nt2 < 4; ++nt2) {
#pragma unroll
      for (int ks2 = 0; ks2 < 4; ++ks2) {
        short8 vb = *(const short8*)&Vbuf[(nt2 * 4 + ks2) * 512 + lane * 8];
        o[nt2] = __builtin_amdgcn_mfma_f32_16x16x32_bf16(ap[ks2], vb, o[nt2], 0, 0, 0);
      }
    }
  }

  if (direct) {
    float inv[4];
#pragma unroll
    for (int i = 0; i < 4; ++i) inv[i] = 1.f / lsum[i];
#pragma unroll
    for (int nt2 = 0; nt2 < 4; ++nt2)
#pragma unroll
      for (int i = 0; i < 4; ++i)
        aout[(size_t)(q0 + wv * 16 + quad * 4 + i) * DIM + h * HDIM + nt2 * 16 + fr] =
            __float2bfloat16(o[nt2][i] * inv[i]);
  } else {
    float* pob = po + (size_t)pid * 4096 + (wv * 16 + quad * 4) * 64 + fr;
#pragma unroll
    for (int nt2 = 0; nt2 < 4; ++nt2)
#pragma unroll
      for (int i = 0; i < 4; ++i) pob[i * 64 + nt2 * 16] = o[nt2][i];
    if (fr == 0) {
#pragma unroll
      for (int i = 0; i < 4; ++i) {
        pm[pid * 64 + wv * 16 + quad * 4 + i] = mrow[i];
        pl[pid * 64 + wv * 16 + quad * 4 + i] = lsum[i];
      }
    }
  }
}

// ---------------------------------------------------------------------------
// Combine 8 KV-slice partials for the global q-blocks (unchanged).
// ---------------------------------------------------------------------------
__global__ __launch_bounds__(256) void combine(const float* __restrict__ po,
                                               const float* __restrict__ pm,
                                               const float* __restrict__ pl,
                                               __hip_bfloat16* __restrict__ aout) {
  int b = blockIdx.x;  // h*4 + chunk
  int h = b >> 2, chunk = b & 3;
  int t = threadIdx.x;
  int row = t >> 2;
  int d0 = (t & 3) * 16;

  float m8[8];
  float newm = -INFINITY;
#pragma unroll
  for (int s = 0; s < 8; ++s) {
    m8[s] = pm[(b * 8 + s) * 64 + row];
    newm = fmaxf(newm, m8[s]);
  }
  float wgt[8], lsum = 0.f;
#pragma unroll
  for (int s = 0; s < 8; ++s) {
    wgt[s] = __expf(m8[s] - newm);
    lsum += pl[(b * 8 + s) * 64 + row] * wgt[s];
  }
  float acc[16];
#pragma unroll
  for (int jj = 0; jj < 16; ++jj) acc[jj] = 0.f;
#pragma unroll
  for (int s = 0; s < 8; ++s) {
    const float* src = po + ((size_t)(b * 8 + s) * 4096) + row * 64 + d0;
#pragma unroll
    for (int j4 = 0; j4 < 4; ++j4) {
      float4 v = *(const float4*)(src + j4 * 4);
      acc[j4 * 4 + 0] += wgt[s] * v.x;
      acc[j4 * 4 + 1] += wgt[s] * v.y;
      acc[j4 * 4 + 2] += wgt[s] * v.z;
      acc[j4 * 4 + 3] += wgt[s] * v.w;
    }
  }
  float inv = 1.f / lsum;
  int qrow = (chunk >> 1) * 3072 + (chunk & 1) * 64 + row;
#pragma unroll
  for (int jj = 0; jj < 16; ++jj)
    aout[(size_t)qrow * DIM + h * HDIM + d0 + jj] = __float2bfloat16(acc[jj] * inv);
}

// ---------------------------------------------------------------------------
extern "C" void kernel_launch(void* const* d_in, const int* in_sizes, int n_in,
                              void* d_out, int out_size, void* d_ws, size_t ws_size,
                              hipStream_t stream) {
  const float* x = (const float*)d_in[0];
  const float* w_qkv = (const float*)d_in[1];
  const float* b_qkv = (const float*)d_in[2];
  const float* w_out = (const float*)d_in[3];
  const float* b_out = (const float*)d_in[4];
  float* out = (float*)d_out;

  // ws layout (bytes):
  //   [0,   24M) bf16 qkv: Q[SEQ][DIM], K[SEQ][DIM], Vt[DIM][SEQ]
  //   [24M, 32M) bf16 x_bf   -- dead after gemm_qkv; reused as po (8MB fp32)
  //   [32M, 38M) bf16 wqkv_bf -- dead after gemm_qkv; first 256KB reused as pm/pl
  //   [38M, 40M) bf16 wout_bf
  //   [40M, 48M) bf16 attn_ws [SEQ][DIM]
  char* wsb = (char*)d_ws;
  __hip_bfloat16* qkv_ws = (__hip_bfloat16*)(wsb);
  __hip_bfloat16* x_bf = (__hip_bfloat16*)(wsb + 24ull * 1024 * 1024);
  __hip_bfloat16* wqkv_bf = (__hip_bfloat16*)(wsb + 32ull * 1024 * 1024);
  __hip_bfloat16* wout_bf = (__hip_bfloat16*)(wsb + 38ull * 1024 * 1024);
  __hip_bfloat16* attn_ws = (__hip_bfloat16*)(wsb + 40ull * 1024 * 1024);
  float* po = (float*)(wsb + 24ull * 1024 * 1024);           // 512*64*64*4 = 8MB
  float* pm = (float*)(wsb + 32ull * 1024 * 1024);           // 128KB
  float* pl = (float*)(wsb + 32ull * 1024 * 1024 + 131072);  // 128KB

  dim3 blk(256);
  downcast3<<<dim3(8192), blk, 0, stream>>>(x, w_qkv, w_out, x_bf, wqkv_bf, wout_bf);
  gemm_qkv<<<dim3(768), blk, 0, stream>>>(x_bf, wqkv_bf, b_qkv, qkv_ws);
  attn_mfma<<<dim3(92, NHEADS), blk, 0, stream>>>(qkv_ws, attn_ws, po, pm, pl);
  combine<<<dim3(64), blk, 0, stream>>>(po, pm, pl, attn_ws);
  gemm_out<<<dim3(256), blk, 0, stream>>>(attn_ws, wout_bf, b_out, out);
}

// Round 9
// 174.507 us; speedup vs baseline: 9.3716x; 1.0203x over previous
//
#include <hip/hip_runtime.h>
#include <hip/hip_bf16.h>
#include <math.h>

// BlockSparseAttention: x[1,4096,1024] fp32; w_qkv[3072,1024], b_qkv[3072],
// w_out[1024,1024], b_out[1024] fp32. out[4096,1024] fp32.
// blocks of 128; global blocks {0,24}; qb attends {0,qb,24} (or all if qb global).

#define SEQ 4096
#define DIM 1024
#define NHEADS 16
#define HDIM 64
#define BS 128
#define ESTRIDE 136   // gemm epilogue staging pad

using short8 = __attribute__((ext_vector_type(8))) short;   // 8 x bf16 bits
using floatx4 = __attribute__((ext_vector_type(4))) float;

__device__ __forceinline__ float bf2f(short s) {
  unsigned u = ((unsigned)(unsigned short)s) << 16;
  return __uint_as_float(u);
}

__device__ __forceinline__ unsigned pack_bf16(float a, float b) {
  __hip_bfloat16 ba = __float2bfloat16(a);
  __hip_bfloat16 bb = __float2bfloat16(b);
  return ((unsigned)*(unsigned short*)&bb << 16) | (unsigned)*(unsigned short*)&ba;
}

__device__ __forceinline__ void gld_lds16(const __hip_bfloat16* g, __hip_bfloat16* l) {
  // 16B per lane, dest = wave-uniform base + lane*16 [guide §5, m97/m104]
  __builtin_amdgcn_global_load_lds(
      (const __attribute__((address_space(1))) unsigned int*)g,
      (__attribute__((address_space(3))) unsigned int*)l, 16, 0, 0);
}

// ---------------------------------------------------------------------------
// merged fp32 -> bf16 downcast for x (4096 blks), w_qkv (3072), w_out (1024)
// ---------------------------------------------------------------------------
__global__ __launch_bounds__(256) void downcast3(
    const float* __restrict__ x, const float* __restrict__ wq,
    const float* __restrict__ wo, __hip_bfloat16* __restrict__ xd,
    __hip_bfloat16* __restrict__ wqd, __hip_bfloat16* __restrict__ wod) {
  int id = blockIdx.x;
  const float* src;
  __hip_bfloat16* dst;
  int base;
  if (id < 4096) { src = x; dst = xd; base = id; }
  else if (id < 7168) { src = wq; dst = wqd; base = id - 4096; }
  else { src = wo; dst = wod; base = id - 7168; }
  int i = (base * 256 + threadIdx.x) * 4;
  float4 v = *(const float4*)(src + i);
  __hip_bfloat16 b0 = __float2bfloat16(v.x);
  __hip_bfloat16 b1 = __float2bfloat16(v.y);
  __hip_bfloat16 b2 = __float2bfloat16(v.z);
  __hip_bfloat16 b3 = __float2bfloat16(v.w);
  ushort4 packed = {*(unsigned short*)&b0, *(unsigned short*)&b1,
                    *(unsigned short*)&b2, *(unsigned short*)&b3};
  *(ushort4*)(((unsigned short*)dst) + i) = packed;
}

// ---------------------------------------------------------------------------
// QKV GEMM (unchanged): m97 K-loop + LDS-staged coalesced epilogue with
// operand swap for Q/K (transposed D) vs V (direct D -> Vt).
// ---------------------------------------------------------------------------
__global__ __launch_bounds__(256) void gemm_qkv(const __hip_bfloat16* __restrict__ Amat,
                                                const __hip_bfloat16* __restrict__ Wmat,
                                                const float* __restrict__ Bias,
                                                __hip_bfloat16* __restrict__ qkv) {
  __shared__ __align__(16) char pool[128 * ESTRIDE * 2];  // 34816 B
  __hip_bfloat16* Asmem = (__hip_bfloat16*)pool;
  __hip_bfloat16* Bsmem = (__hip_bfloat16*)(pool + 8192);
  __hip_bfloat16* Ep = (__hip_bfloat16*)pool;

  const int Kd = DIM;
  const int t = threadIdx.x;
  const int w = t >> 6;
  const int lane = t & 63;
  const int fr = lane & 15;
  const int quad = lane >> 4;
  const int wm = w >> 1, wn = w & 1;

  int id = blockIdx.x;
  int xcd = id & 7, j = id >> 3;
  int m_idx = xcd + (j & 3) * 8;
  int n_idx = j >> 2;
  const int m0 = m_idx * 128;
  const int n0 = n_idx * 128;
  const int s = n0 >> 10;
  const int cc0 = n0 & 1023;
  const bool vmode = (s == 2);

  const __hip_bfloat16* APtr = vmode ? Amat + (size_t)m0 * Kd : Wmat + (size_t)n0 * Kd;
  const __hip_bfloat16* BPtr = vmode ? Wmat + (size_t)n0 * Kd : Amat + (size_t)m0 * Kd;

  floatx4 acc[4][4];
#pragma unroll
  for (int i = 0; i < 4; ++i)
#pragma unroll
    for (int jj = 0; jj < 4; ++jj) acc[i][jj] = (floatx4){0.f, 0.f, 0.f, 0.f};

  for (int kk = 0; kk < Kd / 32; ++kk) {
#pragma unroll
    for (int jj = 0; jj < 2; ++jj) {
      int c = jj * 256 + t;
      int ldso = (jj * 256 + w * 64) * 8;
      gld_lds16(APtr + (size_t)(c >> 2) * Kd + kk * 32 + (c & 3) * 8, &Asmem[ldso]);
      gld_lds16(BPtr + (size_t)(c >> 2) * Kd + kk * 32 + (c & 3) * 8, &Bsmem[ldso]);
    }
    __syncthreads();
    short8 af[4], bf_[4];
#pragma unroll
    for (int mt = 0; mt < 4; ++mt)
      af[mt] = *(const short8*)&Asmem[(wm * 64 + mt * 16 + fr) * 32 + quad * 8];
#pragma unroll
    for (int nt = 0; nt < 4; ++nt)
      bf_[nt] = *(const short8*)&Bsmem[(wn * 64 + nt * 16 + fr) * 32 + quad * 8];
#pragma unroll
    for (int mt = 0; mt < 4; ++mt)
#pragma unroll
      for (int nt = 0; nt < 4; ++nt)
        acc[mt][nt] = __builtin_amdgcn_mfma_f32_16x16x32_bf16(af[mt], bf_[nt],
                                                              acc[mt][nt], 0, 0, 0);
    __syncthreads();
  }

#pragma unroll
  for (int nt = 0; nt < 4; ++nt) {
    int dcol = wn * 64 + nt * 16 + fr;
#pragma unroll
    for (int mt = 0; mt < 4; ++mt) {
      int drow0 = wm * 64 + mt * 16 + quad * 4;
      ushort4 pk;
      unsigned short* pks = (unsigned short*)&pk;
#pragma unroll
      for (int i = 0; i < 4; ++i) {
        __hip_bfloat16 bb = __float2bfloat16(acc[mt][nt][i]);
        pks[i] = *(unsigned short*)&bb;
      }
      *(ushort4*)&Ep[dcol * ESTRIDE + drow0] = pk;
    }
  }
  __syncthreads();

  if (!vmode) {
    __hip_bfloat16* dst = qkv + (size_t)s * SEQ * DIM;
#pragma unroll
    for (int rr = 0; rr < 8; ++rr) {
      int m = rr * 16 + (t >> 4);
      int ch = (t & 15) * 8;
      short8 v8 = *(const short8*)&Ep[m * ESTRIDE + ch];
      float4 b0 = *(const float4*)&Bias[n0 + ch];
      float4 b1 = *(const float4*)&Bias[n0 + ch + 4];
      float bb[8] = {b0.x, b0.y, b0.z, b0.w, b1.x, b1.y, b1.z, b1.w};
      short8 o8;
#pragma unroll
      for (int k = 0; k < 8; ++k) {
        __hip_bfloat16 ob = __float2bfloat16(bf2f(v8[k]) + bb[k]);
        o8[k] = *(short*)&ob;
      }
      *(short8*)&dst[(size_t)(m0 + m) * DIM + cc0 + ch] = o8;
    }
  } else {
    __hip_bfloat16* vt = qkv + 2ull * SEQ * DIM;
#pragma unroll
    for (int rr = 0; rr < 8; ++rr) {
      int nrow = rr * 16 + (t >> 4);
      int ch = (t & 15) * 8;
      float bv = Bias[n0 + nrow];
      short8 v8 = *(const short8*)&Ep[nrow * ESTRIDE + ch];
      short8 o8;
#pragma unroll
      for (int k = 0; k < 8; ++k) {
        __hip_bfloat16 ob = __float2bfloat16(bf2f(v8[k]) + bv);
        o8[k] = *(short*)&ob;
      }
      *(short8*)&vt[(size_t)(cc0 + nrow) * SEQ + m0 + ch] = o8;
    }
  }
}

// ---------------------------------------------------------------------------
// out-proj GEMM: 128x64 tiles -> 512 wgs (2/CU) for latency overlap.
// ---------------------------------------------------------------------------
__global__ __launch_bounds__(256) void gemm_out(const __hip_bfloat16* __restrict__ Amat,
                                                const __hip_bfloat16* __restrict__ Wmat,
                                                const float* __restrict__ Bias,
                                                float* __restrict__ out) {
  __shared__ __align__(16) __hip_bfloat16 Asmem[128 * 32];
  __shared__ __align__(16) __hip_bfloat16 Bsmem[64 * 32];
  const int Kd = DIM;
  const int t = threadIdx.x;
  const int w = t >> 6;
  const int lane = t & 63;
  const int fr = lane & 15;
  const int quad = lane >> 4;
  const int wm = w >> 1, wn = w & 1;
  int id = blockIdx.x;
  int xcd = id & 7, j = id >> 3;       // j in [0,64)
  int m_idx = xcd + (j & 3) * 8;       // 0..31
  int n_idx = j >> 2;                  // 0..15
  const int m0 = m_idx * 128;
  const int n0 = n_idx * 64;
  const __hip_bfloat16* Ablk = Amat + (size_t)m0 * Kd;
  const __hip_bfloat16* Bblk = Wmat + (size_t)n0 * Kd;
  floatx4 acc[4][2];
#pragma unroll
  for (int i = 0; i < 4; ++i)
#pragma unroll
    for (int jj = 0; jj < 2; ++jj) acc[i][jj] = (floatx4){0.f, 0.f, 0.f, 0.f};
  for (int kk = 0; kk < Kd / 32; ++kk) {
#pragma unroll
    for (int jj = 0; jj < 2; ++jj) {
      int c = jj * 256 + t;
      int ldso = (jj * 256 + w * 64) * 8;
      gld_lds16(Ablk + (size_t)(c >> 2) * Kd + kk * 32 + (c & 3) * 8, &Asmem[ldso]);
    }
    gld_lds16(Bblk + (size_t)(t >> 2) * Kd + kk * 32 + (t & 3) * 8, &Bsmem[t * 8]);
    __syncthreads();
    short8 af[4], bf_[2];
#pragma unroll
    for (int mt = 0; mt < 4; ++mt)
      af[mt] = *(const short8*)&Asmem[(wm * 64 + mt * 16 + fr) * 32 + quad * 8];
#pragma unroll
    for (int nt = 0; nt < 2; ++nt)
      bf_[nt] = *(const short8*)&Bsmem[(wn * 32 + nt * 16 + fr) * 32 + quad * 8];
#pragma unroll
    for (int mt = 0; mt < 4; ++mt)
#pragma unroll
      for (int nt = 0; nt < 2; ++nt)
        acc[mt][nt] = __builtin_amdgcn_mfma_f32_16x16x32_bf16(af[mt], bf_[nt],
                                                              acc[mt][nt], 0, 0, 0);
    __syncthreads();
  }
#pragma unroll
  for (int nt = 0; nt < 2; ++nt) {
    int n = n0 + wn * 32 + nt * 16 + fr;
    float bv = Bias[n];
#pragma unroll
    for (int mt = 0; mt < 4; ++mt) {
      int m = m0 + wm * 64 + mt * 16 + quad * 4;
#pragma unroll
      for (int i = 0; i < 4; ++i)
        out[(size_t)(m + i) * DIM + n] = acc[mt][nt][i] + bv;
    }
  }
}

// ---------------------------------------------------------------------------
// MFMA flash attention, S^T formulation.
// St = K.Q^T: lane holds St[key=nt*16+quad*4+i][row=fr] -> lane-local softmax.
// P repack to PV B-operand via shuffle: dest lane (quad,fr), chunk ks2, word p
// needs pki[2*ks2 + (quad>>1)][p&1] from lane fr+16*(2*(quad&1)+(p>>1)).
// FIX vs round 8: nt-select (quad>>1) is DESTINATION-dependent, so shuffle
// BOTH candidates and select after (sel-before-shfl evaluated on src lane).
// PV: O^T = Vt.P^T; O^T C-layout -> contiguous stores. LDS = 32KB.
// ---------------------------------------------------------------------------
__global__ __launch_bounds__(256) void attn_mfma(
    const __hip_bfloat16* __restrict__ qkv,
    __hip_bfloat16* __restrict__ aout,
    float* __restrict__ po, float* __restrict__ pm, float* __restrict__ pl) {
  __shared__ __align__(16) __hip_bfloat16 Kbuf[16 * 512];    // 16KB, 16 frags
  __shared__ __align__(16) __hip_bfloat16 Vbuf[16 * 512];    // 16KB, 16 frags
  const int h = blockIdx.y;
  const int wgid = blockIdx.x;
  const int t = threadIdx.x;
  const int wv = t >> 6;
  const int lane = t & 63;
  const int fr = lane & 15;
  const int quad = lane >> 4;

  int qb, q0, niter, slice = 0, pid = 0;
  bool direct;
  if (wgid < 60) {
    int nb = wgid >> 1;                 // 0..29
    qb = (nb < 23) ? nb + 1 : nb + 2;   // 1..23, 25..31
    q0 = qb * BS + (wgid & 1) * 64;
    niter = 3;
    direct = true;
  } else {
    int gi = wgid - 60;                 // 0..31
    slice = gi & 7;
    int chunk = gi >> 3;                // 0..3
    qb = (chunk >> 1) * 24;             // 0 or 24
    q0 = qb * BS + (chunk & 1) * 64;
    niter = 4;
    direct = false;
    pid = (h * 4 + chunk) * 8 + slice;
  }

  const __hip_bfloat16* Q = qkv;
  const __hip_bfloat16* K = qkv + (size_t)SEQ * DIM;
  const __hip_bfloat16* Vt = qkv + 2ull * SEQ * DIM;  // [DIM][SEQ]

  // Q B-frags: lane holds Q[row=fr][dim=quad*8+j] (+32 for chunk 1)
  short8 qa0, qa1;
  {
    const __hip_bfloat16* qp =
        Q + (size_t)(q0 + wv * 16 + fr) * DIM + h * HDIM + quad * 8;
    qa0 = *(const short8*)(qp);
    qa1 = *(const short8*)(qp + 32);
  }

  float mrow = -INFINITY, lsum = 0.f;
  floatx4 o[4];
#pragma unroll
  for (int i = 0; i < 4; ++i) o[i] = (floatx4){0.f, 0.f, 0.f, 0.f};

  for (int bi = 0; bi < niter; ++bi) {
    int kb = direct ? (bi == 0 ? 0 : (bi == 1 ? qb : 24)) : slice * 4 + bi;

    // ---- cooperative frag-major staging of K and V tiles ----
    const __hip_bfloat16* Kg = K + (size_t)(kb * BS) * DIM + h * HDIM;
    const __hip_bfloat16* Vg = Vt + (size_t)(h * HDIM) * SEQ + kb * BS;
    __syncthreads();  // all waves done reading previous K/V tiles
#pragma unroll
    for (int rr = 0; rr < 4; ++rr) {
      int f = rr * 4 + wv;              // wave-uniform frag id
      int nt = f >> 1, ks = f & 1;      // K frag coords
      gld_lds16(Kg + (size_t)(nt * 16 + fr) * DIM + ks * 32 + quad * 8,
                &Kbuf[f * 512]);
      int nt2 = f >> 2, ks2 = f & 3;    // V frag coords
      gld_lds16(Vg + (size_t)(nt2 * 16 + fr) * SEQ + ks2 * 32 + quad * 8,
                &Vbuf[f * 512]);
    }
    __syncthreads();  // DMA drained

    // ---- St = K.Q^T: lane holds St[key=nt*16+quad*4+i][row=fr] ----
    floatx4 s[8];
#pragma unroll
    for (int nt = 0; nt < 8; ++nt) {
      short8 kf0 = *(const short8*)&Kbuf[(nt * 2 + 0) * 512 + lane * 8];
      short8 kf1 = *(const short8*)&Kbuf[(nt * 2 + 1) * 512 + lane * 8];
      floatx4 acc = {0.f, 0.f, 0.f, 0.f};
      acc = __builtin_amdgcn_mfma_f32_16x16x32_bf16(kf0, qa0, acc, 0, 0, 0);
      acc = __builtin_amdgcn_mfma_f32_16x16x32_bf16(kf1, qa1, acc, 0, 0, 0);
      s[nt] = acc;
    }
#pragma unroll
    for (int nt = 0; nt < 8; ++nt)
#pragma unroll
      for (int i = 0; i < 4; ++i) s[nt][i] *= 0.125f;

    // ---- lane-local online softmax (row = fr) ----
    float rmax = -INFINITY;
#pragma unroll
    for (int nt = 0; nt < 8; ++nt)
#pragma unroll
      for (int i = 0; i < 4; ++i) rmax = fmaxf(rmax, s[nt][i]);
    rmax = fmaxf(rmax, __shfl_xor(rmax, 16, 64));
    rmax = fmaxf(rmax, __shfl_xor(rmax, 32, 64));
    float newm = fmaxf(mrow, rmax);
    float alpha = __expf(mrow - newm);   // first iter: exp(-inf)=0
    float psum = 0.f;
    unsigned pki[8][2];
#pragma unroll
    for (int nt = 0; nt < 8; ++nt) {
      float p0 = __expf(s[nt][0] - newm);
      float p1 = __expf(s[nt][1] - newm);
      float p2 = __expf(s[nt][2] - newm);
      float p3 = __expf(s[nt][3] - newm);
      psum += (p0 + p1) + (p2 + p3);
      pki[nt][0] = pack_bf16(p0, p1);
      pki[nt][1] = pack_bf16(p2, p3);
    }
    psum += __shfl_xor(psum, 16, 64);
    psum += __shfl_xor(psum, 32, 64);
    lsum = lsum * alpha + psum;
    mrow = newm;
#pragma unroll
    for (int nt2 = 0; nt2 < 4; ++nt2)
#pragma unroll
      for (int i = 0; i < 4; ++i) o[nt2][i] *= alpha;

    // ---- in-register repack: P C-layout -> PV B-frags (select AFTER shfl) ----
    union { int w4[4]; short8 s8; } pw[4];
#pragma unroll
    for (int ks2 = 0; ks2 < 4; ++ks2) {
#pragma unroll
      for (int p = 0; p < 4; ++p) {
        int srcl = fr + ((((quad & 1) << 1) + (p >> 1)) << 4);
        int lo = __shfl((int)pki[2 * ks2][p & 1], srcl, 64);
        int hi = __shfl((int)pki[2 * ks2 + 1][p & 1], srcl, 64);
        pw[ks2].w4[p] = (quad & 2) ? hi : lo;
      }
    }

    // ---- PV: O^T += Vt . P^T ----
#pragma unroll
    for (int nt2 = 0; nt2 < 4; ++nt2) {
#pragma unroll
      for (int ks2 = 0; ks2 < 4; ++ks2) {
        short8 vb = *(const short8*)&Vbuf[(nt2 * 4 + ks2) * 512 + lane * 8];
        o[nt2] = __builtin_amdgcn_mfma_f32_16x16x32_bf16(vb, pw[ks2].s8, o[nt2], 0, 0, 0);
      }
    }
  }

  // O^T C-layout: lane holds O[row=fr][d = nt2*16 + quad*4 + i] -> contiguous
  if (direct) {
    float inv = 1.f / lsum;
    __hip_bfloat16* orow = aout + (size_t)(q0 + wv * 16 + fr) * DIM + h * HDIM + quad * 4;
#pragma unroll
    for (int nt2 = 0; nt2 < 4; ++nt2) {
      ushort4 pk;
      unsigned short* pks = (unsigned short*)&pk;
#pragma unroll
      for (int i = 0; i < 4; ++i) {
        __hip_bfloat16 ob = __float2bfloat16(o[nt2][i] * inv);
        pks[i] = *(unsigned short*)&ob;
      }
      *(ushort4*)(orow + nt2 * 16) = pk;
    }
  } else {
    float* pob = po + (size_t)pid * 4096 + (wv * 16 + fr) * 64 + quad * 4;
#pragma unroll
    for (int nt2 = 0; nt2 < 4; ++nt2) {
      float4 v = {o[nt2][0], o[nt2][1], o[nt2][2], o[nt2][3]};
      *(float4*)(pob + nt2 * 16) = v;
    }
    if (quad == 0) {
      pm[pid * 64 + wv * 16 + fr] = mrow;
      pl[pid * 64 + wv * 16 + fr] = lsum;
    }
  }
}

// ---------------------------------------------------------------------------
// Combine 8 KV-slice partials for the global q-blocks (unchanged).
// ---------------------------------------------------------------------------
__global__ __launch_bounds__(256) void combine(const float* __restrict__ po,
                                               const float* __restrict__ pm,
                                               const float* __restrict__ pl,
                                               __hip_bfloat16* __restrict__ aout) {
  int b = blockIdx.x;  // h*4 + chunk
  int h = b >> 2, chunk = b & 3;
  int t = threadIdx.x;
  int row = t >> 2;
  int d0 = (t & 3) * 16;

  float m8[8];
  float newm = -INFINITY;
#pragma unroll
  for (int s = 0; s < 8; ++s) {
    m8[s] = pm[(b * 8 + s) * 64 + row];
    newm = fmaxf(newm, m8[s]);
  }
  float wgt[8], lsum = 0.f;
#pragma unroll
  for (int s = 0; s < 8; ++s) {
    wgt[s] = __expf(m8[s] - newm);
    lsum += pl[(b * 8 + s) * 64 + row] * wgt[s];
  }
  float acc[16];
#pragma unroll
  for (int jj = 0; jj < 16; ++jj) acc[jj] = 0.f;
#pragma unroll
  for (int s = 0; s < 8; ++s) {
    const float* src = po + ((size_t)(b * 8 + s) * 4096) + row * 64 + d0;
#pragma unroll
    for (int j4 = 0; j4 < 4; ++j4) {
      float4 v = *(const float4*)(src + j4 * 4);
      acc[j4 * 4 + 0] += wgt[s] * v.x;
      acc[j4 * 4 + 1] += wgt[s] * v.y;
      acc[j4 * 4 + 2] += wgt[s] * v.z;
      acc[j4 * 4 + 3] += wgt[s] * v.w;
    }
  }
  float inv = 1.f / lsum;
  int qrow = (chunk >> 1) * 3072 + (chunk & 1) * 64 + row;
#pragma unroll
  for (int jj = 0; jj < 16; ++jj)
    aout[(size_t)qrow * DIM + h * HDIM + d0 + jj] = __float2bfloat16(acc[jj] * inv);
}

// ---------------------------------------------------------------------------
extern "C" void kernel_launch(void* const* d_in, const int* in_sizes, int n_in,
                              void* d_out, int out_size, void* d_ws, size_t ws_size,
                              hipStream_t stream) {
  const float* x = (const float*)d_in[0];
  const float* w_qkv = (const float*)d_in[1];
  const float* b_qkv = (const float*)d_in[2];
  const float* w_out = (const float*)d_in[3];
  const float* b_out = (const float*)d_in[4];
  float* out = (float*)d_out;

  // ws layout (bytes):
  //   [0,   24M) bf16 qkv: Q[SEQ][DIM], K[SEQ][DIM], Vt[DIM][SEQ]
  //   [24M, 32M) bf16 x_bf   -- dead after gemm_qkv; reused as po (8MB fp32)
  //   [32M, 38M) bf16 wqkv_bf -- dead after gemm_qkv; first 256KB reused as pm/pl
  //   [38M, 40M) bf16 wout_bf
  //   [40M, 48M) bf16 attn_ws [SEQ][DIM]
  char* wsb = (char*)d_ws;
  __hip_bfloat16* qkv_ws = (__hip_bfloat16*)(wsb);
  __hip_bfloat16* x_bf = (__hip_bfloat16*)(wsb + 24ull * 1024 * 1024);
  __hip_bfloat16* wqkv_bf = (__hip_bfloat16*)(wsb + 32ull * 1024 * 1024);
  __hip_bfloat16* wout_bf = (__hip_bfloat16*)(wsb + 38ull * 1024 * 1024);
  __hip_bfloat16* attn_ws = (__hip_bfloat16*)(wsb + 40ull * 1024 * 1024);
  float* po = (float*)(wsb + 24ull * 1024 * 1024);           // 512*64*64*4 = 8MB
  float* pm = (float*)(wsb + 32ull * 1024 * 1024);           // 128KB
  float* pl = (float*)(wsb + 32ull * 1024 * 1024 + 131072);  // 128KB

  dim3 blk(256);
  downcast3<<<dim3(8192), blk, 0, stream>>>(x, w_qkv, w_out, x_bf, wqkv_bf, wout_bf);
  gemm_qkv<<<dim3(768), blk, 0, stream>>>(x_bf, wqkv_bf, b_qkv, qkv_ws);
  attn_mfma<<<dim3(92, NHEADS), blk, 0, stream>>>(qkv_ws, attn_ws, po, pm, pl);
  combine<<<dim3(64), blk, 0, stream>>>(po, pm, pl, attn_ws);
  gemm_out<<<dim3(512), blk, 0, stream>>>(attn_ws, wout_bf, b_out, out);
}